// Round 5
// baseline (824.077 us; speedup 1.0000x reference)
//
#include <hip/hip_runtime.h>
#include <hip/hip_bf16.h>
#include <math.h>

#define NB 256
#define NN 400
#define NH 128
#define NCOUT 16
#define NNP 416   // padded N (13*32)
#define DP  512   // padded dst rows for maskT
#define KP  416   // padded K for W_adj prep

static constexpr float LOGIT_THRESH = 0.40546510810816444f; // ln(1.5)
static constexpr float LN_EPS = 1e-5f;

typedef __attribute__((ext_vector_type(8))) short short8v;
typedef __attribute__((ext_vector_type(4))) float f32x4;

static __device__ __forceinline__ short f2bf_rne(float f) {
    unsigned u = __float_as_uint(f);
    unsigned r = (u + 0x7fff + ((u >> 16) & 1)) >> 16;
    return (short)r;
}
static __device__ __forceinline__ float bf2f(short s) {
    return __uint_as_float(((unsigned)(unsigned short)s) << 16);
}

// cheap trunc-split: f32 -> hi bf16 (bit-trunc) + lo bf16 (trunc of exact residual).
// total representation error ~2^-14 relative — plenty for the threshold compare.
static __device__ __forceinline__ void split8(float4 u0, float4 u1, short8v& hv, short8v& lv) {
    float x[8] = {u0.x, u0.y, u0.z, u0.w, u1.x, u1.y, u1.z, u1.w};
#pragma unroll
    for (int j = 0; j < 8; ++j) {
        unsigned bb = __float_as_uint(x[j]);
        unsigned hb = bb & 0xffff0000u;
        hv[j] = (short)(bb >> 16);
        lv[j] = (short)(__float_as_uint(x[j] - __uint_as_float(hb)) >> 16);
    }
}

// ---------------- W_adj -> bf16 hi/lo, transposed + padded ----------------
__global__ __launch_bounds__(256) void k_wprep(const float* __restrict__ W,
                                               short* __restrict__ WtH,
                                               short* __restrict__ WtL)
{
    const int k0 = blockIdx.x * 32, d0 = blockIdx.y * 32;
    __shared__ float tile[32][33];
    const int t = threadIdx.x, cc = t & 31, rr = t >> 5;
#pragma unroll
    for (int i = 0; i < 4; ++i) {
        int k = k0 + rr + i * 8, d = d0 + cc;
        tile[rr + i * 8][cc] = (k < NN && d < NN) ? W[k * NN + d] : 0.f;
    }
    __syncthreads();
#pragma unroll
    for (int i = 0; i < 4; ++i) {
        int dr = rr + i * 8;
        int d = d0 + dr, k = k0 + cc;
        float v = tile[cc][dr];
        short h = f2bf_rne(v);
        WtH[d * KP + k] = h;
        WtL[d * KP + k] = f2bf_rne(v - bf2f(h));
    }
}

// ---------------- W (128x128) -> bf16 hi/lo transposed: WT[h][k] ----------------
__global__ __launch_bounds__(256) void k_wprepW(const float* __restrict__ W,
                                                short* __restrict__ WTH,
                                                short* __restrict__ WTL)
{
    const int t = blockIdx.x * 256 + threadIdx.x;   // 16384
    const int h = t >> 7, k = t & 127;
    float v = W[k * NH + h];
    short hi = f2bf_rne(v);
    WTH[h * NH + k] = hi;
    WTL[h * NH + k] = f2bf_rne(v - bf2f(hi));
}

// ---------------- mask GEMM -> maskT[b][d][s], fragment-direct, no LDS, no barriers ----------------
// A = adj rows (f32, trunc-split in-register), B = pre-split WtH/WtL rows (d-major).
// OOB C-rows/cols (>=400) compute garbage from clamped A rows / zero B rows; epilogue skips them.
__global__ __launch_bounds__(256) void k_mask(const float* __restrict__ adj,
                                              const short* __restrict__ WtH,
                                              const short* __restrict__ WtL,
                                              const float* __restrict__ badj,
                                              unsigned char* __restrict__ maskT)
{
    const int b  = blockIdx.z;
    const int s0 = blockIdx.y * 128;
    const int d0 = blockIdx.x * 128;
    const int t  = threadIdx.x;
    const int lane = t & 63, w = t >> 6;
    const int wm = w >> 1, wn = w & 1;
    const int fr = lane & 15, fc = lane >> 4;

    const float* adjb = adj + (long)b * NN * NN;

    const float* aptr[4];
    const short *bhp[4], *blp[4];
#pragma unroll
    for (int m = 0; m < 4; ++m) {
        int s = s0 + wm * 64 + m * 16 + fr;
        int sc = s < NN ? s : (NN - 1);          // clamp: garbage -> unwritten C rows
        aptr[m] = adjb + (long)sc * NN;
    }
#pragma unroll
    for (int n = 0; n < 4; ++n) {
        int d = d0 + wn * 64 + n * 16 + fr;      // d<512, WtH/WtL padded with zeros
        bhp[n] = WtH + (long)d * KP;
        blp[n] = WtL + (long)d * KP;
    }

    f32x4 acc[4][4];
#pragma unroll
    for (int i = 0; i < 4; ++i)
#pragma unroll
        for (int j = 0; j < 4; ++j) acc[i][j] = (f32x4){0.f, 0.f, 0.f, 0.f};

    // 12 full K=32 steps (k <= 383, all in-bounds)
    for (int kt = 0; kt < 12; ++kt) {
        const int k0 = kt * 32 + fc * 8;
        short8v ah[4], al[4], bh[4], bl[4];
#pragma unroll
        for (int m = 0; m < 4; ++m) {
            float4 u0 = *(const float4*)(aptr[m] + k0);
            float4 u1 = *(const float4*)(aptr[m] + k0 + 4);
            split8(u0, u1, ah[m], al[m]);
        }
#pragma unroll
        for (int n = 0; n < 4; ++n) {
            bh[n] = *(const short8v*)(bhp[n] + k0);
            bl[n] = *(const short8v*)(blp[n] + k0);
        }
#pragma unroll
        for (int mi = 0; mi < 4; ++mi)
#pragma unroll
            for (int ni = 0; ni < 4; ++ni) {
                acc[mi][ni] = __builtin_amdgcn_mfma_f32_16x16x32_bf16(ah[mi], bh[ni], acc[mi][ni], 0, 0, 0);
                acc[mi][ni] = __builtin_amdgcn_mfma_f32_16x16x32_bf16(al[mi], bh[ni], acc[mi][ni], 0, 0, 0);
                acc[mi][ni] = __builtin_amdgcn_mfma_f32_16x16x32_bf16(ah[mi], bl[ni], acc[mi][ni], 0, 0, 0);
            }
    }

    // tail: k 384..415 (A valid only for fc<2; B pad columns are stored zeros)
    {
        const int k0 = 384 + fc * 8;
        short8v ah[4], al[4], bh[4], bl[4];
#pragma unroll
        for (int m = 0; m < 4; ++m) {
            if (fc < 2) {
                float4 u0 = *(const float4*)(aptr[m] + k0);
                float4 u1 = *(const float4*)(aptr[m] + k0 + 4);
                split8(u0, u1, ah[m], al[m]);
            } else {
#pragma unroll
                for (int j = 0; j < 8; ++j) { ah[m][j] = 0; al[m][j] = 0; }
            }
        }
#pragma unroll
        for (int n = 0; n < 4; ++n) {
            bh[n] = *(const short8v*)(bhp[n] + k0);
            bl[n] = *(const short8v*)(blp[n] + k0);
        }
#pragma unroll
        for (int mi = 0; mi < 4; ++mi)
#pragma unroll
            for (int ni = 0; ni < 4; ++ni) {
                acc[mi][ni] = __builtin_amdgcn_mfma_f32_16x16x32_bf16(ah[mi], bh[ni], acc[mi][ni], 0, 0, 0);
                acc[mi][ni] = __builtin_amdgcn_mfma_f32_16x16x32_bf16(al[mi], bh[ni], acc[mi][ni], 0, 0, 0);
                acc[mi][ni] = __builtin_amdgcn_mfma_f32_16x16x32_bf16(ah[mi], bl[ni], acc[mi][ni], 0, 0, 0);
            }
    }

    // epilogue -> maskT[d][s] packed uchar4
    unsigned char* mTb = maskT + (long)b * DP * NNP;
    const int colb = d0 + wn * 64 + (lane & 15);            // d
    const int rowb = s0 + wm * 64 + ((lane >> 4) << 2);     // s base
#pragma unroll
    for (int ni = 0; ni < 4; ++ni) {
        const int d = colb + ni * 16;
        if (d >= NN) continue;
        const float bv = badj[d];
#pragma unroll
        for (int mi = 0; mi < 4; ++mi) {
            const int sg = rowb + mi * 16;
            if (sg >= NNP) continue;
            uchar4 pk;
#pragma unroll
            for (int j = 0; j < 4; ++j) {
                const int s = sg + j;
                bool v = (s < NN) && ((acc[mi][ni][j] + bv) > LOGIT_THRESH || s == d);
                ((unsigned char*)&pk)[j] = v ? 1 : 0;
            }
            *(uchar4*)&mTb[(long)d * NNP + sg] = pk;
        }
    }
}

// ---------------- hpT = (hin @ W)^T as bf16, hi/lo-split MFMA, no barriers ----------------
__global__ __launch_bounds__(256) void k_hp(const float* __restrict__ hin,
                                            const short* __restrict__ WTH,
                                            const short* __restrict__ WTL,
                                            short* __restrict__ hpT)
{
    const int b  = blockIdx.y;
    const int s0 = blockIdx.x * 128;
    const int t  = threadIdx.x;
    const int lane = t & 63, w = t >> 6;
    const int wm = w >> 1, wn = w & 1;   // wm: h-half, wn: s-half
    const int fr = lane & 15, fc = lane >> 4;

    const float* hb = hin + (long)b * NN * NH;
    short* hpTb = hpT + (long)b * NH * NNP;

    f32x4 acc[4][4];
#pragma unroll
    for (int m = 0; m < 4; ++m)
#pragma unroll
        for (int n = 0; n < 4; ++n) acc[m][n] = (f32x4){0.f, 0.f, 0.f, 0.f};

    for (int kt = 0; kt < 4; ++kt) {
        const int k0 = kt * 32;
        short8v ah[4], al[4], bh[4], bl[4];
#pragma unroll
        for (int m = 0; m < 4; ++m) {
            const int h = wm * 64 + m * 16 + fr;
            ah[m] = *(const short8v*)&WTH[h * NH + k0 + fc * 8];
            al[m] = *(const short8v*)&WTL[h * NH + k0 + fc * 8];
        }
#pragma unroll
        for (int n = 0; n < 4; ++n) {
            const int s = s0 + wn * 64 + n * 16 + fr;
            float x[8];
            if (s < NN) {
                float4 u0 = *(const float4*)&hb[(long)s * NH + k0 + fc * 8];
                float4 u1 = *(const float4*)&hb[(long)s * NH + k0 + fc * 8 + 4];
                x[0]=u0.x; x[1]=u0.y; x[2]=u0.z; x[3]=u0.w;
                x[4]=u1.x; x[5]=u1.y; x[6]=u1.z; x[7]=u1.w;
            } else {
#pragma unroll
                for (int j = 0; j < 8; ++j) x[j] = 0.f;
            }
#pragma unroll
            for (int j = 0; j < 8; ++j) {
                short hi = f2bf_rne(x[j]);
                bh[n][j] = hi;
                bl[n][j] = f2bf_rne(x[j] - bf2f(hi));
            }
        }
#pragma unroll
        for (int m = 0; m < 4; ++m)
#pragma unroll
            for (int n = 0; n < 4; ++n) {
                acc[m][n] = __builtin_amdgcn_mfma_f32_16x16x32_bf16(ah[m], bh[n], acc[m][n], 0, 0, 0);
                acc[m][n] = __builtin_amdgcn_mfma_f32_16x16x32_bf16(al[m], bh[n], acc[m][n], 0, 0, 0);
                acc[m][n] = __builtin_amdgcn_mfma_f32_16x16x32_bf16(ah[m], bl[n], acc[m][n], 0, 0, 0);
            }
    }

    // store: row = h (fc*4+j), col = s (fr); pads (s in [400,416)) get 0 naturally
#pragma unroll
    for (int m = 0; m < 4; ++m) {
#pragma unroll
        for (int n = 0; n < 4; ++n) {
            const int s = s0 + wn * 64 + n * 16 + fr;
            if (s >= NNP) continue;
#pragma unroll
            for (int j = 0; j < 4; ++j) {
                const int h = wm * 64 + m * 16 + fc * 4 + j;
                hpTb[h * NNP + s] = f2bf_rne(acc[m][n][j]);
            }
        }
    }
}

// ---------------- per-row score pieces: es, ed and exp tables ----------------
__global__ __launch_bounds__(256) void k_e(const short* __restrict__ hpT,
                                           const float* __restrict__ asrc,
                                           const float* __restrict__ adst,
                                           float* __restrict__ esA, float* __restrict__ edA,
                                           float* __restrict__ e1sA, float* __restrict__ e2sA,
                                           float* __restrict__ e1dA, float* __restrict__ e2dA)
{
    const int b = blockIdx.x;
    const int t = threadIdx.x;
    const short* hb = hpT + (long)b * NH * NNP;
    const bool has2 = (t + 256) < NNP;
    float es0 = 0.f, ed0 = 0.f, es1 = 0.f, ed1 = 0.f;
    for (int h = 0; h < NH; ++h) {
        float av = asrc[h], dv = adst[h];
        float v0 = bf2f(hb[h * NNP + t]);
        es0 += v0 * av; ed0 += v0 * dv;
        if (has2) {
            float v1 = bf2f(hb[h * NNP + t + 256]);
            es1 += v1 * av; ed1 += v1 * dv;
        }
    }
    long o = (long)b * NNP + t;
    esA[o] = es0; edA[o] = ed0;
    e1sA[o] = __expf(es0); e2sA[o] = __expf(0.2f * es0);
    e1dA[o] = __expf(ed0); e2dA[o] = __expf(0.2f * ed0);
    if (has2) {
        o += 256;
        esA[o] = es1; edA[o] = ed1;
        e1sA[o] = __expf(es1); e2sA[o] = __expf(0.2f * es1);
        e1dA[o] = __expf(ed1); e2dA[o] = __expf(0.2f * ed1);
    }
}

// ---------------- fragment-direct MFMA aggregation, exp-free P, fused denom ----------------
__global__ __launch_bounds__(256) void k_aggr(const unsigned char* __restrict__ maskT,
                                              const short* __restrict__ hpT,
                                              const float* __restrict__ esA,
                                              const float* __restrict__ edA,
                                              const float* __restrict__ e1sA,
                                              const float* __restrict__ e2sA,
                                              const float* __restrict__ e1dA,
                                              const float* __restrict__ e2dA,
                                              const float* __restrict__ bias,
                                              float* __restrict__ hout)
{
    const int b  = blockIdx.y;
    const int d0 = blockIdx.x * 128;
    const int t  = threadIdx.x;
    const int lane = t & 63, w = t >> 6;
    const int wm = w >> 1, wn = w & 1;
    const int fr = lane & 15, fc = lane >> 4;

    __shared__ float es_l[NNP], e1s_l[NNP], e2s_l[NNP];
    __shared__ float den_l[128];

    for (int i = t; i < NNP; i += 256) {
        const long o = (long)b * NNP + i;
        es_l[i]  = esA[o];
        e1s_l[i] = e1sA[o];
        e2s_l[i] = e2sA[o];
    }

    float edv[4], e1dv[4], e2dv[4];
#pragma unroll
    for (int m = 0; m < 4; ++m) {
        const int d = d0 + wm * 64 + m * 16 + fr;
        const bool v = d < NN;
        const long o = (long)b * NNP + d;
        edv[m]  = v ? edA[o]  : 0.f;
        e1dv[m] = v ? e1dA[o] : 0.f;
        e2dv[m] = v ? e2dA[o] : 0.f;
    }
    __syncthreads();

    f32x4 acc[4][4];
#pragma unroll
    for (int m = 0; m < 4; ++m)
#pragma unroll
        for (int n = 0; n < 4; ++n) acc[m][n] = (f32x4){0.f, 0.f, 0.f, 0.f};
    float den[4] = {0.f, 0.f, 0.f, 0.f};

    const unsigned char* mTb = maskT + (long)b * DP * NNP;
    const short* hTb = hpT + (long)b * NH * NNP;

    for (int kt = 0; kt < 13; ++kt) {
        const int sb = kt * 32 + fc * 8;
        short8v bf_[4];
#pragma unroll
        for (int n = 0; n < 4; ++n) {
            const int h = wn * 64 + n * 16 + fr;
            bf_[n] = *(const short8v*)&hTb[h * NNP + sb];
        }
        float es8[8], e18[8], e28[8];
#pragma unroll
        for (int j = 0; j < 8; ++j) {
            es8[j] = es_l[sb + j];
            e18[j] = e1s_l[sb + j];
            e28[j] = e2s_l[sb + j];
        }
#pragma unroll
        for (int m = 0; m < 4; ++m) {
            const int d = d0 + wm * 64 + m * 16 + fr;
            const unsigned long long mk = *(const unsigned long long*)&mTb[(long)d * NNP + sb];
            short8v pv;
#pragma unroll
            for (int j = 0; j < 8; ++j) {
                const float sc = es8[j] + edv[m];
                float p = sc > 0.f ? e18[j] * e1dv[m] : e28[j] * e2dv[m];
                p = ((mk >> (8 * j)) & 0xffULL) ? p : 0.f;
                den[m] += p;
                pv[j] = f2bf_rne(p);
            }
#pragma unroll
            for (int n = 0; n < 4; ++n)
                acc[m][n] = __builtin_amdgcn_mfma_f32_16x16x32_bf16(pv, bf_[n], acc[m][n], 0, 0, 0);
        }
    }

#pragma unroll
    for (int m = 0; m < 4; ++m) {
        den[m] += __shfl_xor(den[m], 16);
        den[m] += __shfl_xor(den[m], 32);
    }
    if (wn == 0 && fc == 0) {
#pragma unroll
        for (int m = 0; m < 4; ++m) den_l[wm * 64 + m * 16 + fr] = den[m];
    }
    __syncthreads();

    float bvh[4];
#pragma unroll
    for (int n = 0; n < 4; ++n) bvh[n] = bias[wn * 64 + n * 16 + fr];

    float* hb = hout + (long)b * NN * NH;
#pragma unroll
    for (int m = 0; m < 4; ++m) {
#pragma unroll
        for (int j = 0; j < 4; ++j) {
            const int dl = wm * 64 + m * 16 + fc * 4 + j;
            const int d = d0 + dl;
            if (d >= NN) continue;
            const float idn = 1.f / den_l[dl];
#pragma unroll
            for (int n = 0; n < 4; ++n) {
                const int h = wn * 64 + n * 16 + fr;
                hb[(long)d * NH + h] = acc[m][n][j] * idn + bvh[n];
            }
        }
    }
}

// ---------------- in-place LayerNorm(H) + ReLU ----------------
__global__ __launch_bounds__(128) void k_ln_relu(float* __restrict__ h,
                                                 const float* __restrict__ g,
                                                 const float* __restrict__ bb)
{
    const long row = blockIdx.x;
    const int t = threadIdx.x;
    float x = h[row * NH + t];
    __shared__ float red[128];
    red[t] = x;
    __syncthreads();
    for (int off = 64; off > 0; off >>= 1) { if (t < off) red[t] += red[t + off]; __syncthreads(); }
    float mean = red[0] * (1.f / NH);
    __syncthreads();
    float xm = x - mean;
    red[t] = xm * xm;
    __syncthreads();
    for (int off = 64; off > 0; off >>= 1) { if (t < off) red[t] += red[t + off]; __syncthreads(); }
    float var = red[0] * (1.f / NH);
    float y = xm * rsqrtf(var + LN_EPS) * g[t] + bb[t];
    h[row * NH + t] = fmaxf(y, 0.f);
}

// ---------------- mean-pool over N + final linear ----------------
__global__ __launch_bounds__(128) void k_pool_lin(const float* __restrict__ h,
                                                  const float* __restrict__ Wl,
                                                  const float* __restrict__ bl,
                                                  float* __restrict__ out)
{
    const int b = blockIdx.x;
    const int t = threadIdx.x;
    const float* hb = h + (long)b * NN * NH;
    float s = 0.f;
    for (int n = 0; n < NN; ++n) s += hb[(long)n * NH + t];
    __shared__ float gl[128];
    gl[t] = s * (1.f / NN);
    __syncthreads();
    if (t < NCOUT) {
        float o = bl[t];
        for (int k = 0; k < NH; ++k) o += gl[k] * Wl[k * NCOUT + t];
        out[b * NCOUT + t] = o;
    }
}

extern "C" void kernel_launch(void* const* d_in, const int* in_sizes, int n_in,
                              void* d_out, int out_size, void* d_ws, size_t ws_size,
                              hipStream_t stream)
{
    const float* x    = (const float*)d_in[0];
    const float* adj  = (const float*)d_in[1];
    const float* Wadj = (const float*)d_in[4];
    const float* badj = (const float*)d_in[5];
    const float* W1   = (const float*)d_in[6];
    const float* as1  = (const float*)d_in[7];
    const float* ad1  = (const float*)d_in[8];
    const float* b1   = (const float*)d_in[9];
    const float* W2   = (const float*)d_in[10];
    const float* as2  = (const float*)d_in[11];
    const float* ad2  = (const float*)d_in[12];
    const float* b2   = (const float*)d_in[13];
    const float* lng  = (const float*)d_in[14];
    const float* lnb  = (const float*)d_in[15];
    const float* Wlin = (const float*)d_in[16];
    const float* blin = (const float*)d_in[17];
    float* out = (float*)d_out;

    // workspace layout (bytes):
    char* ws = (char*)d_ws;
    unsigned char* maskT = (unsigned char*)ws;        // 256*512*416      = 54,525,952
    short* hpT  = (short*)(ws + 54525952);            // 256*128*416*2    = 27,262,976
    float* hbuf = (float*)(ws + 81788928);            // 256*400*128*4    = 52,428,800
    float* esA  = (float*)(ws + 134217728);           // 6 x 256*416*4
    float* edA  = (float*)(ws + 134643712);
    float* e1sA = (float*)(ws + 135069696);
    float* e2sA = (float*)(ws + 135495680);
    float* e1dA = (float*)(ws + 135921664);
    float* e2dA = (float*)(ws + 136347648);
    short* WtH  = (short*)(ws + 136773632);           // 425,984
    short* WtL  = (short*)(ws + 137199616);           // 425,984
    short* WT1H = (short*)(ws + 137625600);           // 32,768 each
    short* WT1L = (short*)(ws + 137658368);
    short* WT2H = (short*)(ws + 137691136);
    short* WT2L = (short*)(ws + 137723904);           // end 137,756,672

    hipLaunchKernelGGL(k_wprep,  dim3(13, 16), dim3(256), 0, stream, Wadj, WtH, WtL);
    hipLaunchKernelGGL(k_wprepW, dim3(64),     dim3(256), 0, stream, W1, WT1H, WT1L);
    hipLaunchKernelGGL(k_wprepW, dim3(64),     dim3(256), 0, stream, W2, WT2H, WT2L);
    hipLaunchKernelGGL(k_mask,   dim3(4, 4, NB), dim3(256), 0, stream, adj, WtH, WtL, badj, maskT);

    // ---- GAT layer 1 ----
    hipLaunchKernelGGL(k_hp,      dim3(4, NB),   dim3(256), 0, stream, x, WT1H, WT1L, hpT);
    hipLaunchKernelGGL(k_e,       dim3(NB),      dim3(256), 0, stream, hpT, as1, ad1, esA, edA, e1sA, e2sA, e1dA, e2dA);
    hipLaunchKernelGGL(k_aggr,    dim3(4, NB),   dim3(256), 0, stream, maskT, hpT, esA, edA, e1sA, e2sA, e1dA, e2dA, b1, hbuf);
    hipLaunchKernelGGL(k_ln_relu, dim3(NB * NN), dim3(128), 0, stream, hbuf, lng, lnb);

    // ---- GAT layer 2 ----
    hipLaunchKernelGGL(k_hp,      dim3(4, NB),   dim3(256), 0, stream, hbuf, WT2H, WT2L, hpT);
    hipLaunchKernelGGL(k_e,       dim3(NB),      dim3(256), 0, stream, hpT, as2, ad2, esA, edA, e1sA, e2sA, e1dA, e2dA);
    hipLaunchKernelGGL(k_aggr,    dim3(4, NB),   dim3(256), 0, stream, maskT, hpT, esA, edA, e1sA, e2sA, e1dA, e2dA, b2, hbuf);
    hipLaunchKernelGGL(k_ln_relu, dim3(NB * NN), dim3(128), 0, stream, hbuf, lng, lnb);

    // ---- GAT layer 3 (W2 again, no LN/ReLU) ----
    hipLaunchKernelGGL(k_hp,      dim3(4, NB),   dim3(256), 0, stream, hbuf, WT2H, WT2L, hpT);
    hipLaunchKernelGGL(k_e,       dim3(NB),      dim3(256), 0, stream, hpT, as2, ad2, esA, edA, e1sA, e2sA, e1dA, e2dA);
    hipLaunchKernelGGL(k_aggr,    dim3(4, NB),   dim3(256), 0, stream, maskT, hpT, esA, edA, e1sA, e2sA, e1dA, e2dA, b2, hbuf);

    hipLaunchKernelGGL(k_pool_lin, dim3(NB),     dim3(128), 0, stream, hbuf, Wlin, blin, out);
}

// Round 6
// 726.204 us; speedup vs baseline: 1.1348x; 1.1348x over previous
//
#include <hip/hip_runtime.h>
#include <hip/hip_bf16.h>
#include <math.h>

#define NB 256
#define NN 400
#define NH 128
#define NCOUT 16
#define NNP 416   // padded N (13*32)
#define DP  512   // padded dst rows for maskT
#define KP  416   // padded K for W_adj prep

static constexpr float LOGIT_THRESH = 0.40546510810816444f; // ln(1.5)
static constexpr float LN_EPS = 1e-5f;

typedef __attribute__((ext_vector_type(8))) short short8v;
typedef __attribute__((ext_vector_type(4))) float f32x4;

static __device__ __forceinline__ short f2bf_rne(float f) {
    unsigned u = __float_as_uint(f);
    unsigned r = (u + 0x7fff + ((u >> 16) & 1)) >> 16;
    return (short)r;
}
static __device__ __forceinline__ float bf2f(short s) {
    return __uint_as_float(((unsigned)(unsigned short)s) << 16);
}

// cheap trunc-split: f32 -> hi bf16 (bit-trunc) + lo bf16 (trunc of exact residual).
static __device__ __forceinline__ void split8(float4 u0, float4 u1, short8v& hv, short8v& lv) {
    float x[8] = {u0.x, u0.y, u0.z, u0.w, u1.x, u1.y, u1.z, u1.w};
#pragma unroll
    for (int j = 0; j < 8; ++j) {
        unsigned bb = __float_as_uint(x[j]);
        unsigned hb = bb & 0xffff0000u;
        hv[j] = (short)(bb >> 16);
        lv[j] = (short)(__float_as_uint(x[j] - __uint_as_float(hb)) >> 16);
    }
}

// async global->LDS DMA, 16B per lane; lptr is wave-uniform base, HW adds lane*16
static __device__ __forceinline__ void gload16(const void* g, void* l) {
    __builtin_amdgcn_global_load_lds((const __attribute__((address_space(1))) void*)g,
                                     (__attribute__((address_space(3))) void*)l, 16, 0, 0);
}

// ---------------- W_adj -> bf16 hi/lo, transposed + padded ----------------
__global__ __launch_bounds__(256) void k_wprep(const float* __restrict__ W,
                                               short* __restrict__ WtH,
                                               short* __restrict__ WtL)
{
    const int k0 = blockIdx.x * 32, d0 = blockIdx.y * 32;
    __shared__ float tile[32][33];
    const int t = threadIdx.x, cc = t & 31, rr = t >> 5;
#pragma unroll
    for (int i = 0; i < 4; ++i) {
        int k = k0 + rr + i * 8, d = d0 + cc;
        tile[rr + i * 8][cc] = (k < NN && d < NN) ? W[k * NN + d] : 0.f;
    }
    __syncthreads();
#pragma unroll
    for (int i = 0; i < 4; ++i) {
        int dr = rr + i * 8;
        int d = d0 + dr, k = k0 + cc;
        float v = tile[cc][dr];
        short h = f2bf_rne(v);
        WtH[d * KP + k] = h;
        WtL[d * KP + k] = f2bf_rne(v - bf2f(h));
    }
}

// ---------------- W (128x128) -> bf16 hi/lo transposed: WT[h][k] ----------------
__global__ __launch_bounds__(256) void k_wprepW(const float* __restrict__ W,
                                                short* __restrict__ WTH,
                                                short* __restrict__ WTL)
{
    const int t = blockIdx.x * 256 + threadIdx.x;   // 16384
    const int h = t >> 7, k = t & 127;
    float v = W[k * NH + h];
    short hi = f2bf_rne(v);
    WTH[h * NH + k] = hi;
    WTL[h * NH + k] = f2bf_rne(v - bf2f(hi));
}

// ---------------- mask GEMM -> maskT[b][d][s]: m97 structure ----------------
// global_load_lds staging (A f32 + pre-split Bh/Bl), source-pre-swizzled LDS,
// single-buffer 2-barrier K-loop, split-at-read, panel-grouped XCD swizzle.
__global__ __launch_bounds__(256) void k_mask(const float* __restrict__ adj,
                                              const short* __restrict__ WtH,
                                              const short* __restrict__ WtL,
                                              const float* __restrict__ badj,
                                              unsigned char* __restrict__ maskT)
{
    // 1-D grid 4096; group the 4 d0-members of each (b,s0) A-panel on one XCD:
    // dispatch id j -> XCD = j%8 (round-robin); members share j&7.
    const int j   = blockIdx.x;
    const int xcd = j & 7;
    const int li  = j >> 3;                    // 0..511
    const int panel  = xcd * 128 + (li >> 2);  // 0..1023
    const int member = li & 3;
    const int b  = panel >> 2;
    const int s0 = (panel & 3) * 128;
    const int d0 = member * 128;

    const int t = threadIdx.x;
    const int lane = t & 63, w = t >> 6;
    const int wm = w >> 1, wn = w & 1;
    const int fr = lane & 15, fc = lane >> 4;

    __shared__ float As[128 * 32];   // 16KB, chunk-swizzled c^=(row&7)
    __shared__ short Bhs[128 * 32];  // 8KB,  chunk-swizzled c^=((row>>1)&3)
    __shared__ short Bls[128 * 32];  // 8KB

    const float* adjb = adj + (long)b * NN * NN;

    // ---- staging addresses (per-lane global, wave-uniform LDS base) ----
    // A: 4 insts/wave, each 8 rows x 128B; lane: row += lane>>3, slot chunk = lane&7
    long aG[4];
    int  aRow[4];
#pragma unroll
    for (int i = 0; i < 4; ++i) {
        int rloc = w * 32 + i * 8 + (lane >> 3);
        aRow[i] = rloc;
        int srow = s0 + rloc; srow = srow < NN ? srow : NN - 1;   // clamp: pad rows unread
        int c = (lane & 7) ^ (rloc & 7);                           // inverse swizzle on src
        aG[i] = (long)srow * NN + c * 4;                           // float index (k0 added later)
    }
    // B: 2 insts/wave each for hi/lo, 16 rows x 64B; lane: row += lane>>2, chunk = lane&3
    long bG[2];
#pragma unroll
    for (int i = 0; i < 2; ++i) {
        int rloc = w * 32 + i * 16 + (lane >> 2);
        int drow = d0 + rloc;                                      // <512, zero-padded rows
        int c = (lane & 3) ^ ((rloc >> 1) & 3);
        bG[i] = (long)drow * KP + c * 8;                           // short index
    }

    f32x4 acc[4][4];
#pragma unroll
    for (int mi = 0; mi < 4; ++mi)
#pragma unroll
        for (int ni = 0; ni < 4; ++ni) acc[mi][ni] = (f32x4){0.f, 0.f, 0.f, 0.f};

    // fragment-read swizzled chunk indices (row&7 == fr&7, m/n-independent)
    const int ca0 = (2 * fc) ^ (fr & 7);
    const int ca1 = (2 * fc + 1) ^ (fr & 7);
    const int cb  = fc ^ ((fr >> 1) & 3);

    for (int kt = 0; kt < 13; ++kt) {
        const int k0 = kt * 32;
        __syncthreads();   // previous step's readers done -> safe to overwrite
        // ---- stage A (f32) ----
#pragma unroll
        for (int i = 0; i < 4; ++i) {
            long gi = aG[i] + k0;
            if (kt == 12) {   // k 400..415 would run off the row: clamp to row start (x0 later)
                int c = (lane & 7) ^ (aRow[i] & 7);
                if (c >= 4) gi = aG[i] - c * 4;
            }
            gload16(adjb + gi, (char*)As + (w * 32 + i * 8) * 128);
        }
        // ---- stage Bh/Bl (pre-split bf16; k-pad cols are stored zeros) ----
#pragma unroll
        for (int i = 0; i < 2; ++i) {
            gload16(WtH + bG[i] + k0, (char*)Bhs + (w * 32 + i * 16) * 64);
            gload16(WtL + bG[i] + k0, (char*)Bls + (w * 32 + i * 16) * 64);
        }
        __syncthreads();   // compiler drains vmcnt before s_barrier -> LDS ready

        // ---- fragments from LDS ----
        short8v ah[4], al[4], bh[4], bl[4];
#pragma unroll
        for (int m = 0; m < 4; ++m) {
            const int row = wm * 64 + m * 16 + fr;
            float4 u0 = *(const float4*)((const char*)As + row * 128 + ca0 * 16);
            float4 u1 = *(const float4*)((const char*)As + row * 128 + ca1 * 16);
            split8(u0, u1, ah[m], al[m]);
        }
#pragma unroll
        for (int n = 0; n < 4; ++n) {
            const int row = wn * 64 + n * 16 + fr;
            bh[n] = *(const short8v*)((const char*)Bhs + row * 64 + cb * 16);
            bl[n] = *(const short8v*)((const char*)Bls + row * 64 + cb * 16);
        }
#pragma unroll
        for (int mi = 0; mi < 4; ++mi)
#pragma unroll
            for (int ni = 0; ni < 4; ++ni) {
                acc[mi][ni] = __builtin_amdgcn_mfma_f32_16x16x32_bf16(ah[mi], bh[ni], acc[mi][ni], 0, 0, 0);
                acc[mi][ni] = __builtin_amdgcn_mfma_f32_16x16x32_bf16(al[mi], bh[ni], acc[mi][ni], 0, 0, 0);
                acc[mi][ni] = __builtin_amdgcn_mfma_f32_16x16x32_bf16(ah[mi], bl[ni], acc[mi][ni], 0, 0, 0);
            }
    }

    // epilogue -> maskT[d][s] packed uchar4
    unsigned char* mTb = maskT + (long)b * DP * NNP;
    const int colb = d0 + wn * 64 + (lane & 15);            // d
    const int rowb = s0 + wm * 64 + ((lane >> 4) << 2);     // s base
#pragma unroll
    for (int ni = 0; ni < 4; ++ni) {
        const int d = colb + ni * 16;
        if (d >= NN) continue;
        const float bv = badj[d];
#pragma unroll
        for (int mi = 0; mi < 4; ++mi) {
            const int sg = rowb + mi * 16;
            if (sg >= NNP) continue;
            uchar4 pk;
#pragma unroll
            for (int jj = 0; jj < 4; ++jj) {
                const int s = sg + jj;
                bool v = (s < NN) && ((acc[mi][ni][jj] + bv) > LOGIT_THRESH || s == d);
                ((unsigned char*)&pk)[jj] = v ? 1 : 0;
            }
            *(uchar4*)&mTb[(long)d * NNP + sg] = pk;
        }
    }
}

// ---------------- hpT = (hin @ W)^T as bf16, hi/lo-split MFMA, no barriers ----------------
__global__ __launch_bounds__(256) void k_hp(const float* __restrict__ hin,
                                            const short* __restrict__ WTH,
                                            const short* __restrict__ WTL,
                                            short* __restrict__ hpT)
{
    const int b  = blockIdx.y;
    const int s0 = blockIdx.x * 128;
    const int t  = threadIdx.x;
    const int lane = t & 63, w = t >> 6;
    const int wm = w >> 1, wn = w & 1;   // wm: h-half, wn: s-half
    const int fr = lane & 15, fc = lane >> 4;

    const float* hb = hin + (long)b * NN * NH;
    short* hpTb = hpT + (long)b * NH * NNP;

    f32x4 acc[4][4];
#pragma unroll
    for (int m = 0; m < 4; ++m)
#pragma unroll
        for (int n = 0; n < 4; ++n) acc[m][n] = (f32x4){0.f, 0.f, 0.f, 0.f};

    for (int kt = 0; kt < 4; ++kt) {
        const int k0 = kt * 32;
        short8v ah[4], al[4], bh[4], bl[4];
#pragma unroll
        for (int m = 0; m < 4; ++m) {
            const int h = wm * 64 + m * 16 + fr;
            ah[m] = *(const short8v*)&WTH[h * NH + k0 + fc * 8];
            al[m] = *(const short8v*)&WTL[h * NH + k0 + fc * 8];
        }
#pragma unroll
        for (int n = 0; n < 4; ++n) {
            const int s = s0 + wn * 64 + n * 16 + fr;
            float x[8];
            if (s < NN) {
                float4 u0 = *(const float4*)&hb[(long)s * NH + k0 + fc * 8];
                float4 u1 = *(const float4*)&hb[(long)s * NH + k0 + fc * 8 + 4];
                x[0]=u0.x; x[1]=u0.y; x[2]=u0.z; x[3]=u0.w;
                x[4]=u1.x; x[5]=u1.y; x[6]=u1.z; x[7]=u1.w;
            } else {
#pragma unroll
                for (int jj = 0; jj < 8; ++jj) x[jj] = 0.f;
            }
#pragma unroll
            for (int jj = 0; jj < 8; ++jj) {
                short hi = f2bf_rne(x[jj]);
                bh[n][jj] = hi;
                bl[n][jj] = f2bf_rne(x[jj] - bf2f(hi));
            }
        }
#pragma unroll
        for (int m = 0; m < 4; ++m)
#pragma unroll
            for (int n = 0; n < 4; ++n) {
                acc[m][n] = __builtin_amdgcn_mfma_f32_16x16x32_bf16(ah[m], bh[n], acc[m][n], 0, 0, 0);
                acc[m][n] = __builtin_amdgcn_mfma_f32_16x16x32_bf16(al[m], bh[n], acc[m][n], 0, 0, 0);
                acc[m][n] = __builtin_amdgcn_mfma_f32_16x16x32_bf16(ah[m], bl[n], acc[m][n], 0, 0, 0);
            }
    }

#pragma unroll
    for (int m = 0; m < 4; ++m) {
#pragma unroll
        for (int n = 0; n < 4; ++n) {
            const int s = s0 + wn * 64 + n * 16 + fr;
            if (s >= NNP) continue;
#pragma unroll
            for (int jj = 0; jj < 4; ++jj) {
                const int h = wm * 64 + m * 16 + fc * 4 + jj;
                hpTb[h * NNP + s] = f2bf_rne(acc[m][n][jj]);
            }
        }
    }
}

// ---------------- per-row score pieces: es, ed and exp tables ----------------
__global__ __launch_bounds__(256) void k_e(const short* __restrict__ hpT,
                                           const float* __restrict__ asrc,
                                           const float* __restrict__ adst,
                                           float* __restrict__ esA, float* __restrict__ edA,
                                           float* __restrict__ e1sA, float* __restrict__ e2sA,
                                           float* __restrict__ e1dA, float* __restrict__ e2dA)
{
    const int b = blockIdx.x;
    const int t = threadIdx.x;
    const short* hb = hpT + (long)b * NH * NNP;
    const bool has2 = (t + 256) < NNP;
    float es0 = 0.f, ed0 = 0.f, es1 = 0.f, ed1 = 0.f;
    for (int h = 0; h < NH; ++h) {
        float av = asrc[h], dv = adst[h];
        float v0 = bf2f(hb[h * NNP + t]);
        es0 += v0 * av; ed0 += v0 * dv;
        if (has2) {
            float v1 = bf2f(hb[h * NNP + t + 256]);
            es1 += v1 * av; ed1 += v1 * dv;
        }
    }
    long o = (long)b * NNP + t;
    esA[o] = es0; edA[o] = ed0;
    e1sA[o] = __expf(es0); e2sA[o] = __expf(0.2f * es0);
    e1dA[o] = __expf(ed0); e2dA[o] = __expf(0.2f * ed0);
    if (has2) {
        o += 256;
        esA[o] = es1; edA[o] = ed1;
        e1sA[o] = __expf(es1); e2sA[o] = __expf(0.2f * es1);
        e1dA[o] = __expf(ed1); e2dA[o] = __expf(0.2f * ed1);
    }
}

// ---------------- fragment-direct MFMA aggregation, exp-free P, fused denom ----------------
__global__ __launch_bounds__(256) void k_aggr(const unsigned char* __restrict__ maskT,
                                              const short* __restrict__ hpT,
                                              const float* __restrict__ esA,
                                              const float* __restrict__ edA,
                                              const float* __restrict__ e1sA,
                                              const float* __restrict__ e2sA,
                                              const float* __restrict__ e1dA,
                                              const float* __restrict__ e2dA,
                                              const float* __restrict__ bias,
                                              float* __restrict__ hout)
{
    const int b  = blockIdx.y;
    const int d0 = blockIdx.x * 128;
    const int t  = threadIdx.x;
    const int lane = t & 63, w = t >> 6;
    const int wm = w >> 1, wn = w & 1;
    const int fr = lane & 15, fc = lane >> 4;

    __shared__ float es_l[NNP], e1s_l[NNP], e2s_l[NNP];
    __shared__ float den_l[128];

    for (int i = t; i < NNP; i += 256) {
        const long o = (long)b * NNP + i;
        es_l[i]  = esA[o];
        e1s_l[i] = e1sA[o];
        e2s_l[i] = e2sA[o];
    }

    float edv[4], e1dv[4], e2dv[4];
#pragma unroll
    for (int m = 0; m < 4; ++m) {
        const int d = d0 + wm * 64 + m * 16 + fr;
        const bool v = d < NN;
        const long o = (long)b * NNP + d;
        edv[m]  = v ? edA[o]  : 0.f;
        e1dv[m] = v ? e1dA[o] : 0.f;
        e2dv[m] = v ? e2dA[o] : 0.f;
    }
    __syncthreads();

    f32x4 acc[4][4];
#pragma unroll
    for (int m = 0; m < 4; ++m)
#pragma unroll
        for (int n = 0; n < 4; ++n) acc[m][n] = (f32x4){0.f, 0.f, 0.f, 0.f};
    float den[4] = {0.f, 0.f, 0.f, 0.f};

    const unsigned char* mTb = maskT + (long)b * DP * NNP;
    const short* hTb = hpT + (long)b * NH * NNP;

    for (int kt = 0; kt < 13; ++kt) {
        const int sb = kt * 32 + fc * 8;
        short8v bf_[4];
#pragma unroll
        for (int n = 0; n < 4; ++n) {
            const int h = wn * 64 + n * 16 + fr;
            bf_[n] = *(const short8v*)&hTb[h * NNP + sb];
        }
        float es8[8], e18[8], e28[8];
#pragma unroll
        for (int jj = 0; jj < 8; ++jj) {
            es8[jj] = es_l[sb + jj];
            e18[jj] = e1s_l[sb + jj];
            e28[jj] = e2s_l[sb + jj];
        }
#pragma unroll
        for (int m = 0; m < 4; ++m) {
            const int d = d0 + wm * 64 + m * 16 + fr;
            const unsigned long long mk = *(const unsigned long long*)&mTb[(long)d * NNP + sb];
            short8v pv;
#pragma unroll
            for (int jj = 0; jj < 8; ++jj) {
                const float sc = es8[jj] + edv[m];
                float p = sc > 0.f ? e18[jj] * e1dv[m] : e28[jj] * e2dv[m];
                p = ((mk >> (8 * jj)) & 0xffULL) ? p : 0.f;
                den[m] += p;
                pv[jj] = f2bf_rne(p);
            }
#pragma unroll
            for (int n = 0; n < 4; ++n)
                acc[m][n] = __builtin_amdgcn_mfma_f32_16x16x32_bf16(pv, bf_[n], acc[m][n], 0, 0, 0);
        }
    }

#pragma unroll
    for (int m = 0; m < 4; ++m) {
        den[m] += __shfl_xor(den[m], 16);
        den[m] += __shfl_xor(den[m], 32);
    }
    if (wn == 0 && fc == 0) {
#pragma unroll
        for (int m = 0; m < 4; ++m) den_l[wm * 64 + m * 16 + fr] = den[m];
    }
    __syncthreads();

    float bvh[4];
#pragma unroll
    for (int n = 0; n < 4; ++n) bvh[n] = bias[wn * 64 + n * 16 + fr];

    float* hb = hout + (long)b * NN * NH;
#pragma unroll
    for (int m = 0; m < 4; ++m) {
#pragma unroll
        for (int jj = 0; jj < 4; ++jj) {
            const int dl = wm * 64 + m * 16 + fc * 4 + jj;
            const int d = d0 + dl;
            if (d >= NN) continue;
            const float idn = 1.f / den_l[dl];
#pragma unroll
            for (int n = 0; n < 4; ++n) {
                const int h = wn * 64 + n * 16 + fr;
                hb[(long)d * NH + h] = acc[m][n][jj] * idn + bvh[n];
            }
        }
    }
}

// ---------------- in-place LayerNorm(H) + ReLU ----------------
__global__ __launch_bounds__(128) void k_ln_relu(float* __restrict__ h,
                                                 const float* __restrict__ g,
                                                 const float* __restrict__ bb)
{
    const long row = blockIdx.x;
    const int t = threadIdx.x;
    float x = h[row * NH + t];
    __shared__ float red[128];
    red[t] = x;
    __syncthreads();
    for (int off = 64; off > 0; off >>= 1) { if (t < off) red[t] += red[t + off]; __syncthreads(); }
    float mean = red[0] * (1.f / NH);
    __syncthreads();
    float xm = x - mean;
    red[t] = xm * xm;
    __syncthreads();
    for (int off = 64; off > 0; off >>= 1) { if (t < off) red[t] += red[t + off]; __syncthreads(); }
    float var = red[0] * (1.f / NH);
    float y = xm * rsqrtf(var + LN_EPS) * g[t] + bb[t];
    h[row * NH + t] = fmaxf(y, 0.f);
}

// ---------------- mean-pool over N + final linear ----------------
__global__ __launch_bounds__(128) void k_pool_lin(const float* __restrict__ h,
                                                  const float* __restrict__ Wl,
                                                  const float* __restrict__ bl,
                                                  float* __restrict__ out)
{
    const int b = blockIdx.x;
    const int t = threadIdx.x;
    const float* hb = h + (long)b * NN * NH;
    float s = 0.f;
    for (int n = 0; n < NN; ++n) s += hb[(long)n * NH + t];
    __shared__ float gl[128];
    gl[t] = s * (1.f / NN);
    __syncthreads();
    if (t < NCOUT) {
        float o = bl[t];
        for (int k = 0; k < NH; ++k) o += gl[k] * Wl[k * NCOUT + t];
        out[b * NCOUT + t] = o;
    }
}

extern "C" void kernel_launch(void* const* d_in, const int* in_sizes, int n_in,
                              void* d_out, int out_size, void* d_ws, size_t ws_size,
                              hipStream_t stream)
{
    const float* x    = (const float*)d_in[0];
    const float* adj  = (const float*)d_in[1];
    const float* Wadj = (const float*)d_in[4];
    const float* badj = (const float*)d_in[5];
    const float* W1   = (const float*)d_in[6];
    const float* as1  = (const float*)d_in[7];
    const float* ad1  = (const float*)d_in[8];
    const float* b1   = (const float*)d_in[9];
    const float* W2   = (const float*)d_in[10];
    const float* as2  = (const float*)d_in[11];
    const float* ad2  = (const float*)d_in[12];
    const float* b2   = (const float*)d_in[13];
    const float* lng  = (const float*)d_in[14];
    const float* lnb  = (const float*)d_in[15];
    const float* Wlin = (const float*)d_in[16];
    const float* blin = (const float*)d_in[17];
    float* out = (float*)d_out;

    // workspace layout (bytes):
    char* ws = (char*)d_ws;
    unsigned char* maskT = (unsigned char*)ws;        // 256*512*416      = 54,525,952
    short* hpT  = (short*)(ws + 54525952);            // 256*128*416*2    = 27,262,976
    float* hbuf = (float*)(ws + 81788928);            // 256*400*128*4    = 52,428,800
    float* esA  = (float*)(ws + 134217728);           // 6 x 256*416*4
    float* edA  = (float*)(ws + 134643712);
    float* e1sA = (float*)(ws + 135069696);
    float* e2sA = (float*)(ws + 135495680);
    float* e1dA = (float*)(ws + 135921664);
    float* e2dA = (float*)(ws + 136347648);
    short* WtH  = (short*)(ws + 136773632);           // 425,984
    short* WtL  = (short*)(ws + 137199616);           // 425,984
    short* WT1H = (short*)(ws + 137625600);           // 32,768 each
    short* WT1L = (short*)(ws + 137658368);
    short* WT2H = (short*)(ws + 137691136);
    short* WT2L = (short*)(ws + 137723904);           // end 137,756,672

    hipLaunchKernelGGL(k_wprep,  dim3(13, 16), dim3(256), 0, stream, Wadj, WtH, WtL);
    hipLaunchKernelGGL(k_wprepW, dim3(64),     dim3(256), 0, stream, W1, WT1H, WT1L);
    hipLaunchKernelGGL(k_wprepW, dim3(64),     dim3(256), 0, stream, W2, WT2H, WT2L);
    hipLaunchKernelGGL(k_mask,   dim3(4096),   dim3(256), 0, stream, adj, WtH, WtL, badj, maskT);

    // ---- GAT layer 1 ----
    hipLaunchKernelGGL(k_hp,      dim3(4, NB),   dim3(256), 0, stream, x, WT1H, WT1L, hpT);
    hipLaunchKernelGGL(k_e,       dim3(NB),      dim3(256), 0, stream, hpT, as1, ad1, esA, edA, e1sA, e2sA, e1dA, e2dA);
    hipLaunchKernelGGL(k_aggr,    dim3(4, NB),   dim3(256), 0, stream, maskT, hpT, esA, edA, e1sA, e2sA, e1dA, e2dA, b1, hbuf);
    hipLaunchKernelGGL(k_ln_relu, dim3(NB * NN), dim3(128), 0, stream, hbuf, lng, lnb);

    // ---- GAT layer 2 ----
    hipLaunchKernelGGL(k_hp,      dim3(4, NB),   dim3(256), 0, stream, hbuf, WT2H, WT2L, hpT);
    hipLaunchKernelGGL(k_e,       dim3(NB),      dim3(256), 0, stream, hpT, as2, ad2, esA, edA, e1sA, e2sA, e1dA, e2dA);
    hipLaunchKernelGGL(k_aggr,    dim3(4, NB),   dim3(256), 0, stream, maskT, hpT, esA, edA, e1sA, e2sA, e1dA, e2dA, b2, hbuf);
    hipLaunchKernelGGL(k_ln_relu, dim3(NB * NN), dim3(128), 0, stream, hbuf, lng, lnb);

    // ---- GAT layer 3 (W2 again, no LN/ReLU) ----
    hipLaunchKernelGGL(k_hp,      dim3(4, NB),   dim3(256), 0, stream, hbuf, WT2H, WT2L, hpT);
    hipLaunchKernelGGL(k_e,       dim3(NB),      dim3(256), 0, stream, hpT, as2, ad2, esA, edA, e1sA, e2sA, e1dA, e2dA);
    hipLaunchKernelGGL(k_aggr,    dim3(4, NB),   dim3(256), 0, stream, maskT, hpT, esA, edA, e1sA, e2sA, e1dA, e2dA, b2, hbuf);

    hipLaunchKernelGGL(k_pool_lin, dim3(NB),     dim3(128), 0, stream, hbuf, Wlin, blin, out);
}

// Round 7
// 625.244 us; speedup vs baseline: 1.3180x; 1.1615x over previous
//
#include <hip/hip_runtime.h>
#include <hip/hip_bf16.h>
#include <math.h>

#define NB 256
#define NN 400
#define NH 128
#define NCOUT 16
#define NNP 416   // padded N (13*32)
#define DP  512   // padded dst rows for maskT
#define KP  416   // padded K for W_adj prep

static constexpr float LOGIT_THRESH = 0.40546510810816444f; // ln(1.5)
static constexpr float LN_EPS = 1e-5f;

typedef __attribute__((ext_vector_type(8))) short short8v;
typedef __attribute__((ext_vector_type(4))) float f32x4;

static __device__ __forceinline__ short f2bf_rne(float f) {
    unsigned u = __float_as_uint(f);
    unsigned r = (u + 0x7fff + ((u >> 16) & 1)) >> 16;
    return (short)r;
}
static __device__ __forceinline__ float bf2f(short s) {
    return __uint_as_float(((unsigned)(unsigned short)s) << 16);
}

// cheap trunc-split: f32 -> hi bf16 (bit-trunc) + lo bf16 (trunc of exact residual).
static __device__ __forceinline__ void split8(float4 u0, float4 u1, short8v& hv, short8v& lv) {
    float x[8] = {u0.x, u0.y, u0.z, u0.w, u1.x, u1.y, u1.z, u1.w};
#pragma unroll
    for (int j = 0; j < 8; ++j) {
        unsigned bb = __float_as_uint(x[j]);
        unsigned hb = bb & 0xffff0000u;
        hv[j] = (short)(bb >> 16);
        lv[j] = (short)(__float_as_uint(x[j] - __uint_as_float(hb)) >> 16);
    }
}

// async global->LDS DMA, 16B per lane; lptr is wave-uniform base, HW adds lane*16
static __device__ __forceinline__ void gload16(const void* g, void* l) {
    __builtin_amdgcn_global_load_lds((const __attribute__((address_space(1))) void*)g,
                                     (__attribute__((address_space(3))) void*)l, 16, 0, 0);
}

// ---------------- W_adj -> bf16 hi/lo, transposed + padded ----------------
__global__ __launch_bounds__(256) void k_wprep(const float* __restrict__ W,
                                               short* __restrict__ WtH,
                                               short* __restrict__ WtL)
{
    const int k0 = blockIdx.x * 32, d0 = blockIdx.y * 32;
    __shared__ float tile[32][33];
    const int t = threadIdx.x, cc = t & 31, rr = t >> 5;
#pragma unroll
    for (int i = 0; i < 4; ++i) {
        int k = k0 + rr + i * 8, d = d0 + cc;
        tile[rr + i * 8][cc] = (k < NN && d < NN) ? W[k * NN + d] : 0.f;
    }
    __syncthreads();
#pragma unroll
    for (int i = 0; i < 4; ++i) {
        int dr = rr + i * 8;
        int d = d0 + dr, k = k0 + cc;
        float v = tile[cc][dr];
        short h = f2bf_rne(v);
        WtH[d * KP + k] = h;
        WtL[d * KP + k] = f2bf_rne(v - bf2f(h));
    }
}

// ---------------- W (128x128) -> bf16 hi/lo transposed: WT[h][k] ----------------
__global__ __launch_bounds__(256) void k_wprepW(const float* __restrict__ W,
                                                short* __restrict__ WTH,
                                                short* __restrict__ WTL)
{
    const int t = blockIdx.x * 256 + threadIdx.x;   // 16384
    const int h = t >> 7, k = t & 127;
    float v = W[k * NH + h];
    short hi = f2bf_rne(v);
    WTH[h * NH + k] = hi;
    WTL[h * NH + k] = f2bf_rne(v - bf2f(hi));
}

// ---------------- mask GEMM -> maskT[b][d][s]: 2-phase dbuf pipeline ----------------
// global_load_lds staging (A f32 + pre-split Bh/Bl), source-pre-swizzled LDS,
// issue-next-STAGE before compute, single __syncthreads per K-step (vmcnt drain after compute).
__global__ __launch_bounds__(256) void k_mask(const float* __restrict__ adj,
                                              const short* __restrict__ WtH,
                                              const short* __restrict__ WtL,
                                              const float* __restrict__ badj,
                                              unsigned char* __restrict__ maskT)
{
    // 1-D grid 4096; group the 4 d0-members of each (b,s0) A-panel on one XCD.
    const int j   = blockIdx.x;
    const int xcd = j & 7;
    const int li  = j >> 3;                    // 0..511
    const int panel  = xcd * 128 + (li >> 2);  // 0..1023
    const int member = li & 3;
    const int b  = panel >> 2;
    const int s0 = (panel & 3) * 128;
    const int d0 = member * 128;

    const int t = threadIdx.x;
    const int lane = t & 63, w = t >> 6;
    const int wm = w >> 1, wn = w & 1;
    const int fr = lane & 15, fc = lane >> 4;

    __shared__ float As[2][128 * 32];   // 2 x 16KB, chunk-swizzled c^=(row&7)
    __shared__ short Bhs[2][128 * 32];  // 2 x 8KB,  chunk-swizzled c^=((row>>1)&3)
    __shared__ short Bls[2][128 * 32];  // 2 x 8KB

    const float* adjb = adj + (long)b * NN * NN;

    // ---- staging addresses (per-lane global, wave-uniform LDS base) ----
    long aG[4];
    int  aRow[4];
#pragma unroll
    for (int i = 0; i < 4; ++i) {
        int rloc = w * 32 + i * 8 + (lane >> 3);
        aRow[i] = rloc;
        int srow = s0 + rloc; srow = srow < NN ? srow : NN - 1;   // clamp: pad rows unread
        int c = (lane & 7) ^ (rloc & 7);                           // inverse swizzle on src
        aG[i] = (long)srow * NN + c * 4;
    }
    long bG[2];
#pragma unroll
    for (int i = 0; i < 2; ++i) {
        int rloc = w * 32 + i * 16 + (lane >> 2);
        int drow = d0 + rloc;                                      // <512, zero-padded rows
        int c = (lane & 3) ^ ((rloc >> 1) & 3);
        bG[i] = (long)drow * KP + c * 8;
    }

    f32x4 acc[4][4];
#pragma unroll
    for (int mi = 0; mi < 4; ++mi)
#pragma unroll
        for (int ni = 0; ni < 4; ++ni) acc[mi][ni] = (f32x4){0.f, 0.f, 0.f, 0.f};

    const int ca0 = (2 * fc) ^ (fr & 7);
    const int ca1 = (2 * fc + 1) ^ (fr & 7);
    const int cb  = fc ^ ((fr >> 1) & 3);

    #define STAGE(KT, BUF)                                                         \
    do {                                                                           \
        const int k0_ = (KT) * 32;                                                 \
        _Pragma("unroll")                                                          \
        for (int i = 0; i < 4; ++i) {                                              \
            long gi = aG[i] + k0_;                                                 \
            if ((KT) == 12) {                                                      \
                int c = (lane & 7) ^ (aRow[i] & 7);                                \
                if (c >= 4) gi = aG[i] - (long)c * 4;                              \
            }                                                                      \
            gload16(adjb + gi, (char*)&As[BUF][0] + (w * 32 + i * 8) * 128);       \
        }                                                                          \
        _Pragma("unroll")                                                          \
        for (int i = 0; i < 2; ++i) {                                              \
            gload16(WtH + bG[i] + k0_, (char*)&Bhs[BUF][0] + (w * 32 + i * 16) * 64); \
            gload16(WtL + bG[i] + k0_, (char*)&Bls[BUF][0] + (w * 32 + i * 16) * 64); \
        }                                                                          \
    } while (0)

    // prologue
    STAGE(0, 0);
    __syncthreads();          // vmcnt(0) drain + barrier: buf0 ready

    int cur = 0;
    for (int kt = 0; kt < 13; ++kt) {
        // issue next tile's DMA first — flies under this step's compute
        if (kt < 12) STAGE(kt + 1, cur ^ 1);

        // ---- compute on buf[cur] ----
        short8v ah[4], al[4], bh[4], bl[4];
#pragma unroll
        for (int m = 0; m < 4; ++m) {
            const int row = wm * 64 + m * 16 + fr;
            float4 u0 = *(const float4*)((const char*)&As[cur][0] + row * 128 + ca0 * 16);
            float4 u1 = *(const float4*)((const char*)&As[cur][0] + row * 128 + ca1 * 16);
            split8(u0, u1, ah[m], al[m]);
        }
#pragma unroll
        for (int n = 0; n < 4; ++n) {
            const int row = wn * 64 + n * 16 + fr;
            bh[n] = *(const short8v*)((const char*)&Bhs[cur][0] + row * 64 + cb * 16);
            bl[n] = *(const short8v*)((const char*)&Bls[cur][0] + row * 64 + cb * 16);
        }
#pragma unroll
        for (int mi = 0; mi < 4; ++mi)
#pragma unroll
            for (int ni = 0; ni < 4; ++ni) {
                acc[mi][ni] = __builtin_amdgcn_mfma_f32_16x16x32_bf16(ah[mi], bh[ni], acc[mi][ni], 0, 0, 0);
                acc[mi][ni] = __builtin_amdgcn_mfma_f32_16x16x32_bf16(al[mi], bh[ni], acc[mi][ni], 0, 0, 0);
                acc[mi][ni] = __builtin_amdgcn_mfma_f32_16x16x32_bf16(ah[mi], bl[ni], acc[mi][ni], 0, 0, 0);
            }

        // one sync per step: drains this step's issued DMA (vmcnt(0)) AND
        // guarantees all waves finished reading buf[cur] before it's restaged.
        __syncthreads();
        cur ^= 1;
    }
    #undef STAGE

    // epilogue -> maskT[d][s] packed uchar4
    unsigned char* mTb = maskT + (long)b * DP * NNP;
    const int colb = d0 + wn * 64 + (lane & 15);            // d
    const int rowb = s0 + wm * 64 + ((lane >> 4) << 2);     // s base
#pragma unroll
    for (int ni = 0; ni < 4; ++ni) {
        const int d = colb + ni * 16;
        if (d >= NN) continue;
        const float bv = badj[d];
#pragma unroll
        for (int mi = 0; mi < 4; ++mi) {
            const int sg = rowb + mi * 16;
            if (sg >= NNP) continue;
            uchar4 pk;
#pragma unroll
            for (int jj = 0; jj < 4; ++jj) {
                const int s = sg + jj;
                bool v = (s < NN) && ((acc[mi][ni][jj] + bv) > LOGIT_THRESH || s == d);
                ((unsigned char*)&pk)[jj] = v ? 1 : 0;
            }
            *(uchar4*)&mTb[(long)d * NNP + sg] = pk;
        }
    }
}

// ---------------- hpT = (hin @ W)^T as bf16 + FUSED e/exp tables ----------------
// C rows = h (A = W^T pre-split), C cols = s. Block holds ALL 128 h for a 128-s slice,
// so es[s] = sum_h hp[h,s]*a_src[h] reduces in-register + tiny LDS combine.
__global__ __launch_bounds__(256) void k_hp(const float* __restrict__ hin,
                                            const short* __restrict__ WTH,
                                            const short* __restrict__ WTL,
                                            const float* __restrict__ asrc,
                                            const float* __restrict__ adst,
                                            short* __restrict__ hpT,
                                            float* __restrict__ esA, float* __restrict__ edA,
                                            float* __restrict__ e1sA, float* __restrict__ e2sA,
                                            float* __restrict__ e1dA, float* __restrict__ e2dA)
{
    const int b  = blockIdx.y;
    const int s0 = blockIdx.x * 128;
    const int t  = threadIdx.x;
    const int lane = t & 63, w = t >> 6;
    const int wm = w >> 1, wn = w & 1;   // wm: h-half, wn: s-half
    const int fr = lane & 15, fc = lane >> 4;

    const float* hb = hin + (long)b * NN * NH;
    short* hpTb = hpT + (long)b * NH * NNP;

    f32x4 acc[4][4];
#pragma unroll
    for (int m = 0; m < 4; ++m)
#pragma unroll
        for (int n = 0; n < 4; ++n) acc[m][n] = (f32x4){0.f, 0.f, 0.f, 0.f};

    for (int kt = 0; kt < 4; ++kt) {
        const int k0 = kt * 32;
        short8v ah[4], al[4], bh[4], bl[4];
#pragma unroll
        for (int m = 0; m < 4; ++m) {
            const int h = wm * 64 + m * 16 + fr;
            ah[m] = *(const short8v*)&WTH[h * NH + k0 + fc * 8];
            al[m] = *(const short8v*)&WTL[h * NH + k0 + fc * 8];
        }
#pragma unroll
        for (int n = 0; n < 4; ++n) {
            const int s = s0 + wn * 64 + n * 16 + fr;
            float x[8];
            if (s < NN) {
                float4 u0 = *(const float4*)&hb[(long)s * NH + k0 + fc * 8];
                float4 u1 = *(const float4*)&hb[(long)s * NH + k0 + fc * 8 + 4];
                x[0]=u0.x; x[1]=u0.y; x[2]=u0.z; x[3]=u0.w;
                x[4]=u1.x; x[5]=u1.y; x[6]=u1.z; x[7]=u1.w;
            } else {
#pragma unroll
                for (int jj = 0; jj < 8; ++jj) x[jj] = 0.f;
            }
#pragma unroll
            for (int jj = 0; jj < 8; ++jj) {
                short hi = f2bf_rne(x[jj]);
                bh[n][jj] = hi;
                bl[n][jj] = f2bf_rne(x[jj] - bf2f(hi));
            }
        }
#pragma unroll
        for (int m = 0; m < 4; ++m)
#pragma unroll
            for (int n = 0; n < 4; ++n) {
                acc[m][n] = __builtin_amdgcn_mfma_f32_16x16x32_bf16(ah[m], bh[n], acc[m][n], 0, 0, 0);
                acc[m][n] = __builtin_amdgcn_mfma_f32_16x16x32_bf16(al[m], bh[n], acc[m][n], 0, 0, 0);
                acc[m][n] = __builtin_amdgcn_mfma_f32_16x16x32_bf16(ah[m], bl[n], acc[m][n], 0, 0, 0);
            }
    }

    // ---- store hpT bf16 ----
#pragma unroll
    for (int m = 0; m < 4; ++m) {
#pragma unroll
        for (int n = 0; n < 4; ++n) {
            const int s = s0 + wn * 64 + n * 16 + fr;
            if (s >= NNP) continue;
#pragma unroll
            for (int jj = 0; jj < 4; ++jj) {
                const int h = wm * 64 + m * 16 + fc * 4 + jj;
                hpTb[h * NNP + s] = f2bf_rne(acc[m][n][jj]);
            }
        }
    }

    // ---- fused e: per-thread dot over its 16 h, shfl over fc, LDS over wm ----
    __shared__ float esp[2][128], edp[2][128];
    float asv[4][4], adv[4][4];
#pragma unroll
    for (int m = 0; m < 4; ++m)
#pragma unroll
        for (int jj = 0; jj < 4; ++jj) {
            const int h = wm * 64 + m * 16 + fc * 4 + jj;
            asv[m][jj] = asrc[h];
            adv[m][jj] = adst[h];
        }
    float ps[4] = {0.f, 0.f, 0.f, 0.f}, pd[4] = {0.f, 0.f, 0.f, 0.f};
#pragma unroll
    for (int n = 0; n < 4; ++n)
#pragma unroll
        for (int m = 0; m < 4; ++m)
#pragma unroll
            for (int jj = 0; jj < 4; ++jj) {
                ps[n] += acc[m][n][jj] * asv[m][jj];
                pd[n] += acc[m][n][jj] * adv[m][jj];
            }
#pragma unroll
    for (int n = 0; n < 4; ++n) {
        ps[n] += __shfl_xor(ps[n], 16); ps[n] += __shfl_xor(ps[n], 32);
        pd[n] += __shfl_xor(pd[n], 16); pd[n] += __shfl_xor(pd[n], 32);
    }
    if (fc == 0) {
#pragma unroll
        for (int n = 0; n < 4; ++n) {
            esp[wm][wn * 64 + n * 16 + fr] = ps[n];
            edp[wm][wn * 64 + n * 16 + fr] = pd[n];
        }
    }
    __syncthreads();
    if (t < 128) {
        const int s = s0 + t;
        if (s < NNP) {
            const float es = esp[0][t] + esp[1][t];
            const float ed = edp[0][t] + edp[1][t];
            const long o = (long)b * NNP + s;
            esA[o] = es;                edA[o] = ed;
            e1sA[o] = __expf(es);       e2sA[o] = __expf(0.2f * es);
            e1dA[o] = __expf(ed);       e2dA[o] = __expf(0.2f * ed);
        }
    }
}

// ---------------- fragment-direct MFMA aggregation, exp-free P, fused denom ----------------
__global__ __launch_bounds__(256) void k_aggr(const unsigned char* __restrict__ maskT,
                                              const short* __restrict__ hpT,
                                              const float* __restrict__ esA,
                                              const float* __restrict__ edA,
                                              const float* __restrict__ e1sA,
                                              const float* __restrict__ e2sA,
                                              const float* __restrict__ e1dA,
                                              const float* __restrict__ e2dA,
                                              const float* __restrict__ bias,
                                              float* __restrict__ hout)
{
    const int b  = blockIdx.y;
    const int d0 = blockIdx.x * 128;
    const int t  = threadIdx.x;
    const int lane = t & 63, w = t >> 6;
    const int wm = w >> 1, wn = w & 1;
    const int fr = lane & 15, fc = lane >> 4;

    __shared__ float es_l[NNP], e1s_l[NNP], e2s_l[NNP];
    __shared__ float den_l[128];

    for (int i = t; i < NNP; i += 256) {
        const long o = (long)b * NNP + i;
        es_l[i]  = esA[o];
        e1s_l[i] = e1sA[o];
        e2s_l[i] = e2sA[o];
    }

    float edv[4], e1dv[4], e2dv[4];
#pragma unroll
    for (int m = 0; m < 4; ++m) {
        const int d = d0 + wm * 64 + m * 16 + fr;
        const bool v = d < NN;
        const long o = (long)b * NNP + d;
        edv[m]  = v ? edA[o]  : 0.f;
        e1dv[m] = v ? e1dA[o] : 0.f;
        e2dv[m] = v ? e2dA[o] : 0.f;
    }
    __syncthreads();

    f32x4 acc[4][4];
#pragma unroll
    for (int m = 0; m < 4; ++m)
#pragma unroll
        for (int n = 0; n < 4; ++n) acc[m][n] = (f32x4){0.f, 0.f, 0.f, 0.f};
    float den[4] = {0.f, 0.f, 0.f, 0.f};

    const unsigned char* mTb = maskT + (long)b * DP * NNP;
    const short* hTb = hpT + (long)b * NH * NNP;

    for (int kt = 0; kt < 13; ++kt) {
        const int sb = kt * 32 + fc * 8;
        short8v bf_[4];
#pragma unroll
        for (int n = 0; n < 4; ++n) {
            const int h = wn * 64 + n * 16 + fr;
            bf_[n] = *(const short8v*)&hTb[h * NNP + sb];
        }
        float es8[8], e18[8], e28[8];
#pragma unroll
        for (int jj = 0; jj < 8; ++jj) {
            es8[jj] = es_l[sb + jj];
            e18[jj] = e1s_l[sb + jj];
            e28[jj] = e2s_l[sb + jj];
        }
#pragma unroll
        for (int m = 0; m < 4; ++m) {
            const int d = d0 + wm * 64 + m * 16 + fr;
            const unsigned long long mk = *(const unsigned long long*)&mTb[(long)d * NNP + sb];
            short8v pv;
#pragma unroll
            for (int jj = 0; jj < 8; ++jj) {
                const float sc = es8[jj] + edv[m];
                float p = sc > 0.f ? e18[jj] * e1dv[m] : e28[jj] * e2dv[m];
                p = ((mk >> (8 * jj)) & 0xffULL) ? p : 0.f;
                den[m] += p;
                pv[jj] = f2bf_rne(p);
            }
#pragma unroll
            for (int n = 0; n < 4; ++n)
                acc[m][n] = __builtin_amdgcn_mfma_f32_16x16x32_bf16(pv, bf_[n], acc[m][n], 0, 0, 0);
        }
    }

#pragma unroll
    for (int m = 0; m < 4; ++m) {
        den[m] += __shfl_xor(den[m], 16);
        den[m] += __shfl_xor(den[m], 32);
    }
    if (wn == 0 && fc == 0) {
#pragma unroll
        for (int m = 0; m < 4; ++m) den_l[wm * 64 + m * 16 + fr] = den[m];
    }
    __syncthreads();

    float bvh[4];
#pragma unroll
    for (int n = 0; n < 4; ++n) bvh[n] = bias[wn * 64 + n * 16 + fr];

    float* hb = hout + (long)b * NN * NH;
#pragma unroll
    for (int m = 0; m < 4; ++m) {
#pragma unroll
        for (int jj = 0; jj < 4; ++jj) {
            const int dl = wm * 64 + m * 16 + fc * 4 + jj;
            const int d = d0 + dl;
            if (d >= NN) continue;
            const float idn = 1.f / den_l[dl];
#pragma unroll
            for (int n = 0; n < 4; ++n) {
                const int h = wn * 64 + n * 16 + fr;
                hb[(long)d * NH + h] = acc[m][n][jj] * idn + bvh[n];
            }
        }
    }
}

// ---------------- in-place LayerNorm(H) + ReLU ----------------
__global__ __launch_bounds__(128) void k_ln_relu(float* __restrict__ h,
                                                 const float* __restrict__ g,
                                                 const float* __restrict__ bb)
{
    const long row = blockIdx.x;
    const int t = threadIdx.x;
    float x = h[row * NH + t];
    __shared__ float red[128];
    red[t] = x;
    __syncthreads();
    for (int off = 64; off > 0; off >>= 1) { if (t < off) red[t] += red[t + off]; __syncthreads(); }
    float mean = red[0] * (1.f / NH);
    __syncthreads();
    float xm = x - mean;
    red[t] = xm * xm;
    __syncthreads();
    for (int off = 64; off > 0; off >>= 1) { if (t < off) red[t] += red[t + off]; __syncthreads(); }
    float var = red[0] * (1.f / NH);
    float y = xm * rsqrtf(var + LN_EPS) * g[t] + bb[t];
    h[row * NH + t] = fmaxf(y, 0.f);
}

// ---------------- mean-pool over N + final linear ----------------
__global__ __launch_bounds__(128) void k_pool_lin(const float* __restrict__ h,
                                                  const float* __restrict__ Wl,
                                                  const float* __restrict__ bl,
                                                  float* __restrict__ out)
{
    const int b = blockIdx.x;
    const int t = threadIdx.x;
    const float* hb = h + (long)b * NN * NH;
    float s = 0.f;
    for (int n = 0; n < NN; ++n) s += hb[(long)n * NH + t];
    __shared__ float gl[128];
    gl[t] = s * (1.f / NN);
    __syncthreads();
    if (t < NCOUT) {
        float o = bl[t];
        for (int k = 0; k < NH; ++k) o += gl[k] * Wl[k * NCOUT + t];
        out[b * NCOUT + t] = o;
    }
}

extern "C" void kernel_launch(void* const* d_in, const int* in_sizes, int n_in,
                              void* d_out, int out_size, void* d_ws, size_t ws_size,
                              hipStream_t stream)
{
    const float* x    = (const float*)d_in[0];
    const float* adj  = (const float*)d_in[1];
    const float* Wadj = (const float*)d_in[4];
    const float* badj = (const float*)d_in[5];
    const float* W1   = (const float*)d_in[6];
    const float* as1  = (const float*)d_in[7];
    const float* ad1  = (const float*)d_in[8];
    const float* b1   = (const float*)d_in[9];
    const float* W2   = (const float*)d_in[10];
    const float* as2  = (const float*)d_in[11];
    const float* ad2  = (const float*)d_in[12];
    const float* b2   = (const float*)d_in[13];
    const float* lng  = (const float*)d_in[14];
    const float* lnb  = (const float*)d_in[15];
    const float* Wlin = (const float*)d_in[16];
    const float* blin = (const float*)d_in[17];
    float* out = (float*)d_out;

    // workspace layout (bytes):
    char* ws = (char*)d_ws;
    unsigned char* maskT = (unsigned char*)ws;        // 256*512*416      = 54,525,952
    short* hpT  = (short*)(ws + 54525952);            // 256*128*416*2    = 27,262,976
    float* hbuf = (float*)(ws + 81788928);            // 256*400*128*4    = 52,428,800
    float* esA  = (float*)(ws + 134217728);           // 6 x 256*416*4
    float* edA  = (float*)(ws + 134643712);
    float* e1sA = (float*)(ws + 135069696);
    float* e2sA = (float*)(ws + 135495680);
    float* e1dA = (float*)(ws + 135921664);
    float* e2dA = (float*)(ws + 136347648);
    short* WtH  = (short*)(ws + 136773632);           // 425,984
    short* WtL  = (short*)(ws + 137199616);           // 425,984
    short* WT1H = (short*)(ws + 137625600);           // 32,768 each
    short* WT1L = (short*)(ws + 137658368);
    short* WT2H = (short*)(ws + 137691136);
    short* WT2L = (short*)(ws + 137723904);           // end 137,756,672

    hipLaunchKernelGGL(k_wprep,  dim3(13, 16), dim3(256), 0, stream, Wadj, WtH, WtL);
    hipLaunchKernelGGL(k_wprepW, dim3(64),     dim3(256), 0, stream, W1, WT1H, WT1L);
    hipLaunchKernelGGL(k_wprepW, dim3(64),     dim3(256), 0, stream, W2, WT2H, WT2L);
    hipLaunchKernelGGL(k_mask,   dim3(4096),   dim3(256), 0, stream, adj, WtH, WtL, badj, maskT);

    // ---- GAT layer 1 ----
    hipLaunchKernelGGL(k_hp,      dim3(4, NB),   dim3(256), 0, stream, x, WT1H, WT1L, as1, ad1, hpT,
                       esA, edA, e1sA, e2sA, e1dA, e2dA);
    hipLaunchKernelGGL(k_aggr,    dim3(4, NB),   dim3(256), 0, stream, maskT, hpT, esA, edA, e1sA, e2sA, e1dA, e2dA, b1, hbuf);
    hipLaunchKernelGGL(k_ln_relu, dim3(NB * NN), dim3(128), 0, stream, hbuf, lng, lnb);

    // ---- GAT layer 2 ----
    hipLaunchKernelGGL(k_hp,      dim3(4, NB),   dim3(256), 0, stream, hbuf, WT2H, WT2L, as2, ad2, hpT,
                       esA, edA, e1sA, e2sA, e1dA, e2dA);
    hipLaunchKernelGGL(k_aggr,    dim3(4, NB),   dim3(256), 0, stream, maskT, hpT, esA, edA, e1sA, e2sA, e1dA, e2dA, b2, hbuf);
    hipLaunchKernelGGL(k_ln_relu, dim3(NB * NN), dim3(128), 0, stream, hbuf, lng, lnb);

    // ---- GAT layer 3 (W2 again, no LN/ReLU) ----
    hipLaunchKernelGGL(k_hp,      dim3(4, NB),   dim3(256), 0, stream, hbuf, WT2H, WT2L, as2, ad2, hpT,
                       esA, edA, e1sA, e2sA, e1dA, e2dA);
    hipLaunchKernelGGL(k_aggr,    dim3(4, NB),   dim3(256), 0, stream, maskT, hpT, esA, edA, e1sA, e2sA, e1dA, e2dA, b2, hbuf);

    hipLaunchKernelGGL(k_pool_lin, dim3(NB),     dim3(128), 0, stream, hbuf, Wlin, blin, out);
}

// Round 8
// 591.856 us; speedup vs baseline: 1.3924x; 1.0564x over previous
//
#include <hip/hip_runtime.h>
#include <hip/hip_bf16.h>
#include <math.h>

#define NB 256
#define NN 400
#define NH 128
#define NCOUT 16
#define NNP 416   // padded N (13*32)
#define DP  512   // padded dst rows for maskT
#define KP  416   // padded K for W_adj prep

static constexpr float LOGIT_THRESH = 0.40546510810816444f; // ln(1.5)
static constexpr float LN_EPS = 1e-5f;

typedef __attribute__((ext_vector_type(8))) short short8v;
typedef __attribute__((ext_vector_type(4))) float f32x4;

static __device__ __forceinline__ short f2bf_rne(float f) {
    unsigned u = __float_as_uint(f);
    unsigned r = (u + 0x7fff + ((u >> 16) & 1)) >> 16;
    return (short)r;
}
static __device__ __forceinline__ float bf2f(short s) {
    return __uint_as_float(((unsigned)(unsigned short)s) << 16);
}

// cheap trunc-split: f32 -> hi bf16 (bit-trunc) + lo bf16 (trunc of exact residual).
static __device__ __forceinline__ void split8(float4 u0, float4 u1, short8v& hv, short8v& lv) {
    float x[8] = {u0.x, u0.y, u0.z, u0.w, u1.x, u1.y, u1.z, u1.w};
#pragma unroll
    for (int j = 0; j < 8; ++j) {
        unsigned bb = __float_as_uint(x[j]);
        unsigned hb = bb & 0xffff0000u;
        hv[j] = (short)(bb >> 16);
        lv[j] = (short)(__float_as_uint(x[j] - __uint_as_float(hb)) >> 16);
    }
}

// async global->LDS DMA, 16B per lane; lptr is wave-uniform base, HW adds lane*16
static __device__ __forceinline__ void gload16(const void* g, void* l) {
    __builtin_amdgcn_global_load_lds((const __attribute__((address_space(1))) void*)g,
                                     (__attribute__((address_space(3))) void*)l, 16, 0, 0);
}

// ---------------- W_adj -> bf16 hi/lo, transposed + padded ----------------
__global__ __launch_bounds__(256) void k_wprep(const float* __restrict__ W,
                                               short* __restrict__ WtH,
                                               short* __restrict__ WtL)
{
    const int k0 = blockIdx.x * 32, d0 = blockIdx.y * 32;
    __shared__ float tile[32][33];
    const int t = threadIdx.x, cc = t & 31, rr = t >> 5;
#pragma unroll
    for (int i = 0; i < 4; ++i) {
        int k = k0 + rr + i * 8, d = d0 + cc;
        tile[rr + i * 8][cc] = (k < NN && d < NN) ? W[k * NN + d] : 0.f;
    }
    __syncthreads();
#pragma unroll
    for (int i = 0; i < 4; ++i) {
        int dr = rr + i * 8;
        int d = d0 + dr, k = k0 + cc;
        float v = tile[cc][dr];
        short h = f2bf_rne(v);
        WtH[d * KP + k] = h;
        WtL[d * KP + k] = f2bf_rne(v - bf2f(h));
    }
}

// ---------------- W (128x128) -> bf16 hi/lo transposed: WT[h][k] ----------------
__global__ __launch_bounds__(256) void k_wprepW(const float* __restrict__ W,
                                                short* __restrict__ WTH,
                                                short* __restrict__ WTL)
{
    const int t = blockIdx.x * 256 + threadIdx.x;   // 16384
    const int h = t >> 7, k = t & 127;
    float v = W[k * NH + h];
    short hi = f2bf_rne(v);
    WTH[h * NH + k] = hi;
    WTL[h * NH + k] = f2bf_rne(v - bf2f(hi));
}

// ---------------- mask GEMM -> maskT[b][d][s]: 128x256 tile, 8 waves, dbuf DMA ----------------
__global__ __launch_bounds__(512) void k_mask(const float* __restrict__ adj,
                                              const short* __restrict__ WtH,
                                              const short* __restrict__ WtL,
                                              const float* __restrict__ badj,
                                              unsigned char* __restrict__ maskT)
{
    // grid 2048; the 2 d0-members of each (b,s0) A-panel share an XCD.
    const int j   = blockIdx.x;
    const int xcd = j & 7;
    const int li  = j >> 3;                    // 0..255
    const int panel  = xcd * 128 + (li >> 1);  // 0..1023
    const int member = li & 1;
    const int b  = panel >> 2;
    const int s0 = (panel & 3) * 128;
    const int d0 = member * 256;

    const int t = threadIdx.x;
    const int lane = t & 63, w = t >> 6;       // w 0..7
    const int wm = w >> 2, wn = w & 3;         // wm: s-half, wn: d-quarter
    const int fr = lane & 15, fc = lane >> 4;

    __shared__ float As[2][128 * 32];   // 2 x 16KB, chunk-swizzled c^=(row&7)
    __shared__ short Bhs[2][256 * 32];  // 2 x 16KB, chunk-swizzled c^=((row>>1)&3)
    __shared__ short Bls[2][256 * 32];  // 2 x 16KB

    const float* adjb = adj + (long)b * NN * NN;

    // staging addresses (per-lane global, wave-uniform LDS base)
    long aG[2];
    int  aRow[2];
#pragma unroll
    for (int i = 0; i < 2; ++i) {
        int rloc = w * 16 + i * 8 + (lane >> 3);           // 0..127
        aRow[i] = rloc;
        int srow = s0 + rloc; srow = srow < NN ? srow : NN - 1;
        int c = (lane & 7) ^ (rloc & 7);                   // inverse swizzle on src
        aG[i] = (long)srow * NN + c * 4;
    }
    long bG[2];
#pragma unroll
    for (int i = 0; i < 2; ++i) {
        int rloc = w * 32 + i * 16 + (lane >> 2);          // 0..255
        int drow = d0 + rloc;                              // <512, zero-padded rows
        int c = (lane & 3) ^ ((rloc >> 1) & 3);
        bG[i] = (long)drow * KP + c * 8;
    }

    f32x4 acc[4][4];
#pragma unroll
    for (int mi = 0; mi < 4; ++mi)
#pragma unroll
        for (int ni = 0; ni < 4; ++ni) acc[mi][ni] = (f32x4){0.f, 0.f, 0.f, 0.f};

    const int ca0 = (2 * fc) ^ (fr & 7);
    const int ca1 = (2 * fc + 1) ^ (fr & 7);
    const int cb  = fc ^ ((fr >> 1) & 3);

    #define STAGE(KT, BUF)                                                            \
    do {                                                                              \
        const int k0_ = (KT) * 32;                                                    \
        _Pragma("unroll")                                                             \
        for (int i = 0; i < 2; ++i) {                                                 \
            long gi = aG[i] + k0_;                                                    \
            if ((KT) == 12) {                                                         \
                int c = (lane & 7) ^ (aRow[i] & 7);                                   \
                if (c >= 4) gi = aG[i] - (long)c * 4;   /* A garbage x B zero-pad */  \
            }                                                                         \
            gload16(adjb + gi, (char*)&As[BUF][0] + (w * 16 + i * 8) * 128);          \
        }                                                                             \
        _Pragma("unroll")                                                             \
        for (int i = 0; i < 2; ++i) {                                                 \
            gload16(WtH + bG[i] + k0_, (char*)&Bhs[BUF][0] + (w * 32 + i * 16) * 64); \
            gload16(WtL + bG[i] + k0_, (char*)&Bls[BUF][0] + (w * 32 + i * 16) * 64); \
        }                                                                             \
    } while (0)

    STAGE(0, 0);
    __syncthreads();

    int cur = 0;
    for (int kt = 0; kt < 13; ++kt) {
        if (kt < 12) STAGE(kt + 1, cur ^ 1);

        short8v ah[4], al[4], bh[4], bl[4];
#pragma unroll
        for (int m = 0; m < 4; ++m) {
            const int row = wm * 64 + m * 16 + fr;
            float4 u0 = *(const float4*)((const char*)&As[cur][0] + row * 128 + ca0 * 16);
            float4 u1 = *(const float4*)((const char*)&As[cur][0] + row * 128 + ca1 * 16);
            split8(u0, u1, ah[m], al[m]);
        }
#pragma unroll
        for (int n = 0; n < 4; ++n) {
            const int row = wn * 64 + n * 16 + fr;
            bh[n] = *(const short8v*)((const char*)&Bhs[cur][0] + row * 64 + cb * 16);
            bl[n] = *(const short8v*)((const char*)&Bls[cur][0] + row * 64 + cb * 16);
        }
#pragma unroll
        for (int mi = 0; mi < 4; ++mi)
#pragma unroll
            for (int ni = 0; ni < 4; ++ni) {
                acc[mi][ni] = __builtin_amdgcn_mfma_f32_16x16x32_bf16(ah[mi], bh[ni], acc[mi][ni], 0, 0, 0);
                acc[mi][ni] = __builtin_amdgcn_mfma_f32_16x16x32_bf16(al[mi], bh[ni], acc[mi][ni], 0, 0, 0);
                acc[mi][ni] = __builtin_amdgcn_mfma_f32_16x16x32_bf16(ah[mi], bl[ni], acc[mi][ni], 0, 0, 0);
            }

        __syncthreads();   // drains this step's DMA + all waves done reading cur
        cur ^= 1;
    }
    #undef STAGE

    // epilogue -> maskT[d][s] packed uchar4
    unsigned char* mTb = maskT + (long)b * DP * NNP;
    const int colb = d0 + wn * 64 + (lane & 15);            // d
    const int rowb = s0 + wm * 64 + ((lane >> 4) << 2);     // s base
#pragma unroll
    for (int ni = 0; ni < 4; ++ni) {
        const int d = colb + ni * 16;
        if (d >= NN) continue;
        const float bv = badj[d];
#pragma unroll
        for (int mi = 0; mi < 4; ++mi) {
            const int sg = rowb + mi * 16;
            if (sg >= NNP) continue;
            uchar4 pk;
#pragma unroll
            for (int jj = 0; jj < 4; ++jj) {
                const int s = sg + jj;
                bool v = (s < NN) && ((acc[mi][ni][jj] + bv) > LOGIT_THRESH || s == d);
                ((unsigned char*)&pk)[jj] = v ? 1 : 0;
            }
            *(uchar4*)&mTb[(long)d * NNP + sg] = pk;
        }
    }
}

// ---------------- hpT = (hin @ W)^T as bf16 + FUSED e/exp tables ----------------
__global__ __launch_bounds__(256) void k_hp(const float* __restrict__ hin,
                                            const short* __restrict__ WTH,
                                            const short* __restrict__ WTL,
                                            const float* __restrict__ asrc,
                                            const float* __restrict__ adst,
                                            short* __restrict__ hpT,
                                            float* __restrict__ esA, float* __restrict__ edA,
                                            float* __restrict__ e1sA, float* __restrict__ e2sA,
                                            float* __restrict__ e1dA, float* __restrict__ e2dA)
{
    const int b  = blockIdx.y;
    const int s0 = blockIdx.x * 128;
    const int t  = threadIdx.x;
    const int lane = t & 63, w = t >> 6;
    const int wm = w >> 1, wn = w & 1;   // wm: h-half, wn: s-half
    const int fr = lane & 15, fc = lane >> 4;

    const float* hb = hin + (long)b * NN * NH;
    short* hpTb = hpT + (long)b * NH * NNP;

    f32x4 acc[4][4];
#pragma unroll
    for (int m = 0; m < 4; ++m)
#pragma unroll
        for (int n = 0; n < 4; ++n) acc[m][n] = (f32x4){0.f, 0.f, 0.f, 0.f};

    for (int kt = 0; kt < 4; ++kt) {
        const int k0 = kt * 32;
        short8v ah[4], al[4], bh[4], bl[4];
#pragma unroll
        for (int m = 0; m < 4; ++m) {
            const int h = wm * 64 + m * 16 + fr;
            ah[m] = *(const short8v*)&WTH[h * NH + k0 + fc * 8];
            al[m] = *(const short8v*)&WTL[h * NH + k0 + fc * 8];
        }
#pragma unroll
        for (int n = 0; n < 4; ++n) {
            const int s = s0 + wn * 64 + n * 16 + fr;
            float x[8];
            if (s < NN) {
                float4 u0 = *(const float4*)&hb[(long)s * NH + k0 + fc * 8];
                float4 u1 = *(const float4*)&hb[(long)s * NH + k0 + fc * 8 + 4];
                x[0]=u0.x; x[1]=u0.y; x[2]=u0.z; x[3]=u0.w;
                x[4]=u1.x; x[5]=u1.y; x[6]=u1.z; x[7]=u1.w;
            } else {
#pragma unroll
                for (int jj = 0; jj < 8; ++jj) x[jj] = 0.f;
            }
#pragma unroll
            for (int jj = 0; jj < 8; ++jj) {
                short hi = f2bf_rne(x[jj]);
                bh[n][jj] = hi;
                bl[n][jj] = f2bf_rne(x[jj] - bf2f(hi));
            }
        }
#pragma unroll
        for (int m = 0; m < 4; ++m)
#pragma unroll
            for (int n = 0; n < 4; ++n) {
                acc[m][n] = __builtin_amdgcn_mfma_f32_16x16x32_bf16(ah[m], bh[n], acc[m][n], 0, 0, 0);
                acc[m][n] = __builtin_amdgcn_mfma_f32_16x16x32_bf16(al[m], bh[n], acc[m][n], 0, 0, 0);
                acc[m][n] = __builtin_amdgcn_mfma_f32_16x16x32_bf16(ah[m], bl[n], acc[m][n], 0, 0, 0);
            }
    }

#pragma unroll
    for (int m = 0; m < 4; ++m) {
#pragma unroll
        for (int n = 0; n < 4; ++n) {
            const int s = s0 + wn * 64 + n * 16 + fr;
            if (s >= NNP) continue;
#pragma unroll
            for (int jj = 0; jj < 4; ++jj) {
                const int h = wm * 64 + m * 16 + fc * 4 + jj;
                hpTb[h * NNP + s] = f2bf_rne(acc[m][n][jj]);
            }
        }
    }

    // fused e: per-thread dot over its 16 h, shfl over fc, LDS over wm
    __shared__ float esp[2][128], edp[2][128];
    float asv[4][4], adv[4][4];
#pragma unroll
    for (int m = 0; m < 4; ++m)
#pragma unroll
        for (int jj = 0; jj < 4; ++jj) {
            const int h = wm * 64 + m * 16 + fc * 4 + jj;
            asv[m][jj] = asrc[h];
            adv[m][jj] = adst[h];
        }
    float ps[4] = {0.f, 0.f, 0.f, 0.f}, pd[4] = {0.f, 0.f, 0.f, 0.f};
#pragma unroll
    for (int n = 0; n < 4; ++n)
#pragma unroll
        for (int m = 0; m < 4; ++m)
#pragma unroll
            for (int jj = 0; jj < 4; ++jj) {
                ps[n] += acc[m][n][jj] * asv[m][jj];
                pd[n] += acc[m][n][jj] * adv[m][jj];
            }
#pragma unroll
    for (int n = 0; n < 4; ++n) {
        ps[n] += __shfl_xor(ps[n], 16); ps[n] += __shfl_xor(ps[n], 32);
        pd[n] += __shfl_xor(pd[n], 16); pd[n] += __shfl_xor(pd[n], 32);
    }
    if (fc == 0) {
#pragma unroll
        for (int n = 0; n < 4; ++n) {
            esp[wm][wn * 64 + n * 16 + fr] = ps[n];
            edp[wm][wn * 64 + n * 16 + fr] = pd[n];
        }
    }
    __syncthreads();
    if (t < 128) {
        const int s = s0 + t;
        if (s < NNP) {
            const float es = esp[0][t] + esp[1][t];
            const float ed = edp[0][t] + edp[1][t];
            const long o = (long)b * NNP + s;
            esA[o] = es;                edA[o] = ed;
            e1sA[o] = __expf(es);       e2sA[o] = __expf(0.2f * es);
            e1dA[o] = __expf(ed);       e2dA[o] = __expf(0.2f * ed);
        }
    }
}

// ---------------- fragment-direct MFMA aggregation + optional fused LN/ReLU ----------------
template<int DO_LN>
__global__ __launch_bounds__(256) void k_aggr(const unsigned char* __restrict__ maskT,
                                              const short* __restrict__ hpT,
                                              const float* __restrict__ esA,
                                              const float* __restrict__ edA,
                                              const float* __restrict__ e1sA,
                                              const float* __restrict__ e2sA,
                                              const float* __restrict__ e1dA,
                                              const float* __restrict__ e2dA,
                                              const float* __restrict__ bias,
                                              const float* __restrict__ lng,
                                              const float* __restrict__ lnb,
                                              float* __restrict__ hout)
{
    const int b  = blockIdx.y;
    const int d0 = blockIdx.x * 128;
    const int t  = threadIdx.x;
    const int lane = t & 63, w = t >> 6;
    const int wm = w >> 1, wn = w & 1;
    const int fr = lane & 15, fc = lane >> 4;

    __shared__ float es_l[NNP], e1s_l[NNP], e2s_l[NNP];
    __shared__ float den_l[128];
    __shared__ float lngl[128], lnbl[128];

    for (int i = t; i < NNP; i += 256) {
        const long o = (long)b * NNP + i;
        es_l[i]  = esA[o];
        e1s_l[i] = e1sA[o];
        e2s_l[i] = e2sA[o];
    }
    if (DO_LN && t < 128) { lngl[t] = lng[t]; lnbl[t] = lnb[t]; }

    float edv[4], e1dv[4], e2dv[4];
#pragma unroll
    for (int m = 0; m < 4; ++m) {
        const int d = d0 + wm * 64 + m * 16 + fr;
        const bool v = d < NN;
        const long o = (long)b * NNP + d;
        edv[m]  = v ? edA[o]  : 0.f;
        e1dv[m] = v ? e1dA[o] : 0.f;
        e2dv[m] = v ? e2dA[o] : 0.f;
    }
    __syncthreads();

    f32x4 acc[4][4];
#pragma unroll
    for (int m = 0; m < 4; ++m)
#pragma unroll
        for (int n = 0; n < 4; ++n) acc[m][n] = (f32x4){0.f, 0.f, 0.f, 0.f};
    float den[4] = {0.f, 0.f, 0.f, 0.f};

    const unsigned char* mTb = maskT + (long)b * DP * NNP;
    const short* hTb = hpT + (long)b * NH * NNP;

    for (int kt = 0; kt < 13; ++kt) {
        const int sb = kt * 32 + fc * 8;
        short8v bf_[4];
#pragma unroll
        for (int n = 0; n < 4; ++n) {
            const int h = wn * 64 + n * 16 + fr;
            bf_[n] = *(const short8v*)&hTb[h * NNP + sb];
        }
        float es8[8], e18[8], e28[8];
#pragma unroll
        for (int jj = 0; jj < 8; ++jj) {
            es8[jj] = es_l[sb + jj];
            e18[jj] = e1s_l[sb + jj];
            e28[jj] = e2s_l[sb + jj];
        }
#pragma unroll
        for (int m = 0; m < 4; ++m) {
            const int d = d0 + wm * 64 + m * 16 + fr;
            const unsigned long long mk = *(const unsigned long long*)&mTb[(long)d * NNP + sb];
            short8v pv;
#pragma unroll
            for (int jj = 0; jj < 8; ++jj) {
                const float sc = es8[jj] + edv[m];
                float p = sc > 0.f ? e18[jj] * e1dv[m] : e28[jj] * e2dv[m];
                p = ((mk >> (8 * jj)) & 0xffULL) ? p : 0.f;
                den[m] += p;
                pv[jj] = f2bf_rne(p);
            }
#pragma unroll
            for (int n = 0; n < 4; ++n)
                acc[m][n] = __builtin_amdgcn_mfma_f32_16x16x32_bf16(pv, bf_[n], acc[m][n], 0, 0, 0);
        }
    }

#pragma unroll
    for (int m = 0; m < 4; ++m) {
        den[m] += __shfl_xor(den[m], 16);
        den[m] += __shfl_xor(den[m], 32);
    }
    if (wn == 0 && fc == 0) {
#pragma unroll
        for (int m = 0; m < 4; ++m) den_l[wm * 64 + m * 16 + fr] = den[m];
    }
    __syncthreads();

    float bvh[4];
#pragma unroll
    for (int n = 0; n < 4; ++n) bvh[n] = bias[wn * 64 + n * 16 + fr];

    float* hb = hout + (long)b * NN * NH;

    if (DO_LN) {
        __shared__ float Cm[32][132];
        for (int m = 0; m < 4; ++m) {
            // scatter this m-frag's 32 d-rows into LDS (scaled + biased)
#pragma unroll
            for (int jj = 0; jj < 4; ++jj) {
                const int dl = wm * 64 + m * 16 + fc * 4 + jj;
                const float idn = 1.f / den_l[dl];
                const int r = wm * 16 + fc * 4 + jj;
#pragma unroll
                for (int n = 0; n < 4; ++n)
                    Cm[r][wn * 64 + n * 16 + fr] = acc[m][n][jj] * idn + bvh[n];
            }
            __syncthreads();
            // LN+ReLU: 8 threads per row, shfl-combined stats
            {
                const int r = t >> 3, seg = t & 7;
                float s1 = 0.f, s2 = 0.f;
#pragma unroll
                for (int q = 0; q < 16; q += 4) {
                    float4 v = *(float4*)&Cm[r][seg * 16 + q];
                    s1 += v.x + v.y + v.z + v.w;
                    s2 += v.x * v.x + v.y * v.y + v.z * v.z + v.w * v.w;
                }
                s1 += __shfl_xor(s1, 1); s2 += __shfl_xor(s2, 1);
                s1 += __shfl_xor(s1, 2); s2 += __shfl_xor(s2, 2);
                s1 += __shfl_xor(s1, 4); s2 += __shfl_xor(s2, 4);
                const float mean = s1 * (1.f / 128.f);
                const float var  = s2 * (1.f / 128.f) - mean * mean;
                const float inv  = rsqrtf(fmaxf(var, 0.f) + LN_EPS);
                const int d = d0 + (r >> 4) * 64 + m * 16 + (r & 15);
                if (d < NN) {
                    float* po = hb + (long)d * NH;
#pragma unroll
                    for (int q = 0; q < 16; q += 4) {
                        const int cl = seg * 16 + q;
                        float4 v = *(float4*)&Cm[r][cl];
                        float4 o;
                        o.x = fmaxf((v.x - mean) * inv * lngl[cl]     + lnbl[cl],     0.f);
                        o.y = fmaxf((v.y - mean) * inv * lngl[cl + 1] + lnbl[cl + 1], 0.f);
                        o.z = fmaxf((v.z - mean) * inv * lngl[cl + 2] + lnbl[cl + 2], 0.f);
                        o.w = fmaxf((v.w - mean) * inv * lngl[cl + 3] + lnbl[cl + 3], 0.f);
                        *(float4*)&po[cl] = o;
                    }
                }
            }
            __syncthreads();
        }
    } else {
#pragma unroll
        for (int m = 0; m < 4; ++m) {
#pragma unroll
            for (int jj = 0; jj < 4; ++jj) {
                const int dl = wm * 64 + m * 16 + fc * 4 + jj;
                const int d = d0 + dl;
                if (d >= NN) continue;
                const float idn = 1.f / den_l[dl];
#pragma unroll
                for (int n = 0; n < 4; ++n) {
                    const int h = wn * 64 + n * 16 + fr;
                    hb[(long)d * NH + h] = acc[m][n][jj] * idn + bvh[n];
                }
            }
        }
    }
}

// ---------------- mean-pool over N + final linear ----------------
__global__ __launch_bounds__(128) void k_pool_lin(const float* __restrict__ h,
                                                  const float* __restrict__ Wl,
                                                  const float* __restrict__ bl,
                                                  float* __restrict__ out)
{
    const int b = blockIdx.x;
    const int t = threadIdx.x;
    const float* hb = h + (long)b * NN * NH;
    float s = 0.f;
    for (int n = 0; n < NN; ++n) s += hb[(long)n * NH + t];
    __shared__ float gl[128];
    gl[t] = s * (1.f / NN);
    __syncthreads();
    if (t < NCOUT) {
        float o = bl[t];
        for (int k = 0; k < NH; ++k) o += gl[k] * Wl[k * NCOUT + t];
        out[b * NCOUT + t] = o;
    }
}

extern "C" void kernel_launch(void* const* d_in, const int* in_sizes, int n_in,
                              void* d_out, int out_size, void* d_ws, size_t ws_size,
                              hipStream_t stream)
{
    const float* x    = (const float*)d_in[0];
    const float* adj  = (const float*)d_in[1];
    const float* Wadj = (const float*)d_in[4];
    const float* badj = (const float*)d_in[5];
    const float* W1   = (const float*)d_in[6];
    const float* as1  = (const float*)d_in[7];
    const float* ad1  = (const float*)d_in[8];
    const float* b1   = (const float*)d_in[9];
    const float* W2   = (const float*)d_in[10];
    const float* as2  = (const float*)d_in[11];
    const float* ad2  = (const float*)d_in[12];
    const float* b2   = (const float*)d_in[13];
    const float* lng  = (const float*)d_in[14];
    const float* lnb  = (const float*)d_in[15];
    const float* Wlin = (const float*)d_in[16];
    const float* blin = (const float*)d_in[17];
    float* out = (float*)d_out;

    char* ws = (char*)d_ws;
    unsigned char* maskT = (unsigned char*)ws;        // 256*512*416      = 54,525,952
    short* hpT  = (short*)(ws + 54525952);            // 256*128*416*2    = 27,262,976
    float* hbuf = (float*)(ws + 81788928);            // 256*400*128*4    = 52,428,800
    float* esA  = (float*)(ws + 134217728);           // 6 x 256*416*4
    float* edA  = (float*)(ws + 134643712);
    float* e1sA = (float*)(ws + 135069696);
    float* e2sA = (float*)(ws + 135495680);
    float* e1dA = (float*)(ws + 135921664);
    float* e2dA = (float*)(ws + 136347648);
    short* WtH  = (short*)(ws + 136773632);           // 425,984
    short* WtL  = (short*)(ws + 137199616);           // 425,984
    short* WT1H = (short*)(ws + 137625600);           // 32,768 each
    short* WT1L = (short*)(ws + 137658368);
    short* WT2H = (short*)(ws + 137691136);
    short* WT2L = (short*)(ws + 137723904);           // end 137,756,672

    k_wprep<<<dim3(13, 16), dim3(256), 0, stream>>>(Wadj, WtH, WtL);
    k_wprepW<<<dim3(64), dim3(256), 0, stream>>>(W1, WT1H, WT1L);
    k_wprepW<<<dim3(64), dim3(256), 0, stream>>>(W2, WT2H, WT2L);
    k_mask<<<dim3(2048), dim3(512), 0, stream>>>(adj, WtH, WtL, badj, maskT);

    // ---- GAT layer 1 ----
    k_hp<<<dim3(4, NB), dim3(256), 0, stream>>>(x, WT1H, WT1L, as1, ad1, hpT,
                                                esA, edA, e1sA, e2sA, e1dA, e2dA);
    k_aggr<1><<<dim3(4, NB), dim3(256), 0, stream>>>(maskT, hpT, esA, edA, e1sA, e2sA, e1dA, e2dA,
                                                     b1, lng, lnb, hbuf);

    // ---- GAT layer 2 ----
    k_hp<<<dim3(4, NB), dim3(256), 0, stream>>>(hbuf, WT2H, WT2L, as2, ad2, hpT,
                                                esA, edA, e1sA, e2sA, e1dA, e2dA);
    k_aggr<1><<<dim3(4, NB), dim3(256), 0, stream>>>(maskT, hpT, esA, edA, e1sA, e2sA, e1dA, e2dA,
                                                     b2, lng, lnb, hbuf);

    // ---- GAT layer 3 (W2 again, no LN/ReLU) ----
    k_hp<<<dim3(4, NB), dim3(256), 0, stream>>>(hbuf, WT2H, WT2L, as2, ad2, hpT,
                                                esA, edA, e1sA, e2sA, e1dA, e2dA);
    k_aggr<0><<<dim3(4, NB), dim3(256), 0, stream>>>(maskT, hpT, esA, edA, e1sA, e2sA, e1dA, e2dA,
                                                     b2, lng, lnb, hbuf);

    k_pool_lin<<<dim3(NB), dim3(128), 0, stream>>>(hbuf, Wlin, blin, out);
}

// Round 9
// 556.545 us; speedup vs baseline: 1.4807x; 1.0634x over previous
//
#include <hip/hip_runtime.h>
#include <hip/hip_bf16.h>
#include <math.h>

#define NB 256
#define NN 400
#define NH 128
#define NCOUT 16
#define NNP 416   // padded N (13*32)
#define DP  512   // padded dst rows for maskT
#define KP  416   // padded K for W_adj prep

static constexpr float LOGIT_THRESH = 0.40546510810816444f; // ln(1.5)
static constexpr float LN_EPS = 1e-5f;

typedef __attribute__((ext_vector_type(8))) short short8v;
typedef __attribute__((ext_vector_type(4))) float f32x4;

static __device__ __forceinline__ short f2bf_rne(float f) {
    unsigned u = __float_as_uint(f);
    unsigned r = (u + 0x7fff + ((u >> 16) & 1)) >> 16;
    return (short)r;
}
static __device__ __forceinline__ float bf2f(short s) {
    return __uint_as_float(((unsigned)(unsigned short)s) << 16);
}

// cheap trunc-split: f32 -> hi bf16 (bit-trunc) + lo bf16 (trunc of exact residual).
static __device__ __forceinline__ void split8(float4 u0, float4 u1, short8v& hv, short8v& lv) {
    float x[8] = {u0.x, u0.y, u0.z, u0.w, u1.x, u1.y, u1.z, u1.w};
#pragma unroll
    for (int j = 0; j < 8; ++j) {
        unsigned bb = __float_as_uint(x[j]);
        unsigned hb = bb & 0xffff0000u;
        hv[j] = (short)(bb >> 16);
        lv[j] = (short)(__float_as_uint(x[j] - __uint_as_float(hb)) >> 16);
    }
}

// async global->LDS DMA, 16B per lane; lptr is wave-uniform base, HW adds lane*16
static __device__ __forceinline__ void gload16(const void* g, void* l) {
    __builtin_amdgcn_global_load_lds((const __attribute__((address_space(1))) void*)g,
                                     (__attribute__((address_space(3))) void*)l, 16, 0, 0);
}

// ---------------- W_adj -> bf16 hi/lo, transposed + padded ----------------
__global__ __launch_bounds__(256) void k_wprep(const float* __restrict__ W,
                                               short* __restrict__ WtH,
                                               short* __restrict__ WtL)
{
    const int k0 = blockIdx.x * 32, d0 = blockIdx.y * 32;
    __shared__ float tile[32][33];
    const int t = threadIdx.x, cc = t & 31, rr = t >> 5;
#pragma unroll
    for (int i = 0; i < 4; ++i) {
        int k = k0 + rr + i * 8, d = d0 + cc;
        tile[rr + i * 8][cc] = (k < NN && d < NN) ? W[k * NN + d] : 0.f;
    }
    __syncthreads();
#pragma unroll
    for (int i = 0; i < 4; ++i) {
        int dr = rr + i * 8;
        int d = d0 + dr, k = k0 + cc;
        float v = tile[cc][dr];
        short h = f2bf_rne(v);
        WtH[d * KP + k] = h;
        WtL[d * KP + k] = f2bf_rne(v - bf2f(h));
    }
}

// ---------------- W (128x128) -> bf16 hi/lo transposed: WT[h][k] ----------------
__global__ __launch_bounds__(256) void k_wprepW(const float* __restrict__ W,
                                                short* __restrict__ WTH,
                                                short* __restrict__ WTL)
{
    const int t = blockIdx.x * 256 + threadIdx.x;   // 16384
    const int h = t >> 7, k = t & 127;
    float v = W[k * NH + h];
    short hi = f2bf_rne(v);
    WTH[h * NH + k] = hi;
    WTL[h * NH + k] = f2bf_rne(v - bf2f(hi));
}

// ---------------- mask GEMM -> maskT[b][d][s]: dbuf + counted-vmcnt pipeline ----------------
// 128x128 tile, 4 waves, 64KB dbuf LDS (2 blocks/CU). Raw s_barrier + s_waitcnt vmcnt(8):
// next tile's DMA stays in flight across the barrier; we only wait for the tile issued a
// full iteration earlier (latency hidden under compute + barriers).
__global__ __launch_bounds__(256) void k_mask(const float* __restrict__ adj,
                                              const short* __restrict__ WtH,
                                              const short* __restrict__ WtL,
                                              const float* __restrict__ badj,
                                              unsigned char* __restrict__ maskT)
{
    // 1-D grid 4096; group the 4 d0-members of each (b,s0) A-panel on one XCD.
    const int j   = blockIdx.x;
    const int xcd = j & 7;
    const int li  = j >> 3;                    // 0..511
    const int panel  = xcd * 128 + (li >> 2);  // 0..1023
    const int member = li & 3;
    const int b  = panel >> 2;
    const int s0 = (panel & 3) * 128;
    const int d0 = member * 128;

    const int t = threadIdx.x;
    const int lane = t & 63, w = t >> 6;
    const int wm = w >> 1, wn = w & 1;
    const int fr = lane & 15, fc = lane >> 4;

    __shared__ float As[2][128 * 32];   // 2 x 16KB, chunk-swizzled c^=(row&7)
    __shared__ short Bhs[2][128 * 32];  // 2 x 8KB,  chunk-swizzled c^=((row>>1)&3)
    __shared__ short Bls[2][128 * 32];  // 2 x 8KB

    const float* adjb = adj + (long)b * NN * NN;

    // staging addresses (per-lane global, wave-uniform LDS base)
    long aG[4];
    int  aRow[4];
#pragma unroll
    for (int i = 0; i < 4; ++i) {
        int rloc = w * 32 + i * 8 + (lane >> 3);
        aRow[i] = rloc;
        int srow = s0 + rloc; srow = srow < NN ? srow : NN - 1;
        int c = (lane & 7) ^ (rloc & 7);                   // inverse swizzle on src
        aG[i] = (long)srow * NN + c * 4;
    }
    long bG[2];
#pragma unroll
    for (int i = 0; i < 2; ++i) {
        int rloc = w * 32 + i * 16 + (lane >> 2);
        int drow = d0 + rloc;                              // <512, zero-padded rows
        int c = (lane & 3) ^ ((rloc >> 1) & 3);
        bG[i] = (long)drow * KP + c * 8;
    }

    f32x4 acc[4][4];
#pragma unroll
    for (int mi = 0; mi < 4; ++mi)
#pragma unroll
        for (int ni = 0; ni < 4; ++ni) acc[mi][ni] = (f32x4){0.f, 0.f, 0.f, 0.f};

    const int ca0 = (2 * fc) ^ (fr & 7);
    const int ca1 = (2 * fc + 1) ^ (fr & 7);
    const int cb  = fc ^ ((fr >> 1) & 3);

    #define STAGE(KT, BUF)                                                            \
    do {                                                                              \
        const int k0_ = (KT) * 32;                                                    \
        _Pragma("unroll")                                                             \
        for (int i = 0; i < 4; ++i) {                                                 \
            long gi = aG[i] + k0_;                                                    \
            if ((KT) == 12) {                                                         \
                int c = (lane & 7) ^ (aRow[i] & 7);                                   \
                if (c >= 4) gi = aG[i] - (long)c * 4;   /* A garbage x B zero-pad */  \
            }                                                                         \
            gload16(adjb + gi, (char*)&As[BUF][0] + (w * 32 + i * 8) * 128);          \
        }                                                                             \
        _Pragma("unroll")                                                             \
        for (int i = 0; i < 2; ++i) {                                                 \
            gload16(WtH + bG[i] + k0_, (char*)&Bhs[BUF][0] + (w * 32 + i * 16) * 64); \
            gload16(WtL + bG[i] + k0_, (char*)&Bls[BUF][0] + (w * 32 + i * 16) * 64); \
        }                                                                             \
    } while (0)

    // prologue: stage tile 0, full drain
    STAGE(0, 0);
    asm volatile("s_waitcnt vmcnt(0)" ::: "memory");
    __builtin_amdgcn_s_barrier();

    int cur = 0;
    for (int kt = 0; kt < 13; ++kt) {
        // (1) everyone finished reading buf[cur^1] in the previous compute
        __builtin_amdgcn_s_barrier();
        // (2) issue next tile into buf[cur^1] — stays in flight across the wait below
        if (kt < 12) STAGE(kt + 1, cur ^ 1);
        // (3) wait ONLY for tile kt (issued one full iteration ago): the 8 newest
        //     outstanding loads are tile kt+1's, the older ones (tile kt) must retire.
        if (kt < 12) asm volatile("s_waitcnt vmcnt(8)" ::: "memory");
        else         asm volatile("s_waitcnt vmcnt(0)" ::: "memory");
        __builtin_amdgcn_s_barrier();
        __builtin_amdgcn_sched_barrier(0);   // fence: no ds_read hoisted above the wait

        // ---- compute on buf[cur] (tile kt) ----
        short8v ah[4], al[4], bh[4], bl[4];
#pragma unroll
        for (int m = 0; m < 4; ++m) {
            const int row = wm * 64 + m * 16 + fr;
            float4 u0 = *(const float4*)((const char*)&As[cur][0] + row * 128 + ca0 * 16);
            float4 u1 = *(const float4*)((const char*)&As[cur][0] + row * 128 + ca1 * 16);
            split8(u0, u1, ah[m], al[m]);
        }
#pragma unroll
        for (int n = 0; n < 4; ++n) {
            const int row = wn * 64 + n * 16 + fr;
            bh[n] = *(const short8v*)((const char*)&Bhs[cur][0] + row * 64 + cb * 16);
            bl[n] = *(const short8v*)((const char*)&Bls[cur][0] + row * 64 + cb * 16);
        }
#pragma unroll
        for (int mi = 0; mi < 4; ++mi)
#pragma unroll
            for (int ni = 0; ni < 4; ++ni) {
                acc[mi][ni] = __builtin_amdgcn_mfma_f32_16x16x32_bf16(ah[mi], bh[ni], acc[mi][ni], 0, 0, 0);
                acc[mi][ni] = __builtin_amdgcn_mfma_f32_16x16x32_bf16(al[mi], bh[ni], acc[mi][ni], 0, 0, 0);
                acc[mi][ni] = __builtin_amdgcn_mfma_f32_16x16x32_bf16(ah[mi], bl[ni], acc[mi][ni], 0, 0, 0);
            }
        cur ^= 1;
    }
    #undef STAGE

    // epilogue -> maskT[d][s] packed uchar4
    unsigned char* mTb = maskT + (long)b * DP * NNP;
    const int colb = d0 + wn * 64 + (lane & 15);            // d
    const int rowb = s0 + wm * 64 + ((lane >> 4) << 2);     // s base
#pragma unroll
    for (int ni = 0; ni < 4; ++ni) {
        const int d = colb + ni * 16;
        if (d >= NN) continue;
        const float bv = badj[d];
#pragma unroll
        for (int mi = 0; mi < 4; ++mi) {
            const int sg = rowb + mi * 16;
            if (sg >= NNP) continue;
            uchar4 pk;
#pragma unroll
            for (int jj = 0; jj < 4; ++jj) {
                const int s = sg + jj;
                bool v = (s < NN) && ((acc[mi][ni][jj] + bv) > LOGIT_THRESH || s == d);
                ((unsigned char*)&pk)[jj] = v ? 1 : 0;
            }
            *(uchar4*)&mTb[(long)d * NNP + sg] = pk;
        }
    }
}

// ---------------- hpT = (hin @ W)^T as bf16 + FUSED e/exp tables ----------------
__global__ __launch_bounds__(256) void k_hp(const float* __restrict__ hin,
                                            const short* __restrict__ WTH,
                                            const short* __restrict__ WTL,
                                            const float* __restrict__ asrc,
                                            const float* __restrict__ adst,
                                            short* __restrict__ hpT,
                                            float* __restrict__ esA, float* __restrict__ edA,
                                            float* __restrict__ e1sA, float* __restrict__ e2sA,
                                            float* __restrict__ e1dA, float* __restrict__ e2dA)
{
    const int b  = blockIdx.y;
    const int s0 = blockIdx.x * 128;
    const int t  = threadIdx.x;
    const int lane = t & 63, w = t >> 6;
    const int wm = w >> 1, wn = w & 1;   // wm: h-half, wn: s-half
    const int fr = lane & 15, fc = lane >> 4;

    const float* hb = hin + (long)b * NN * NH;
    short* hpTb = hpT + (long)b * NH * NNP;

    f32x4 acc[4][4];
#pragma unroll
    for (int m = 0; m < 4; ++m)
#pragma unroll
        for (int n = 0; n < 4; ++n) acc[m][n] = (f32x4){0.f, 0.f, 0.f, 0.f};

    for (int kt = 0; kt < 4; ++kt) {
        const int k0 = kt * 32;
        short8v ah[4], al[4], bh[4], bl[4];
#pragma unroll
        for (int m = 0; m < 4; ++m) {
            const int h = wm * 64 + m * 16 + fr;
            ah[m] = *(const short8v*)&WTH[h * NH + k0 + fc * 8];
            al[m] = *(const short8v*)&WTL[h * NH + k0 + fc * 8];
        }
#pragma unroll
        for (int n = 0; n < 4; ++n) {
            const int s = s0 + wn * 64 + n * 16 + fr;
            float x[8];
            if (s < NN) {
                float4 u0 = *(const float4*)&hb[(long)s * NH + k0 + fc * 8];
                float4 u1 = *(const float4*)&hb[(long)s * NH + k0 + fc * 8 + 4];
                x[0]=u0.x; x[1]=u0.y; x[2]=u0.z; x[3]=u0.w;
                x[4]=u1.x; x[5]=u1.y; x[6]=u1.z; x[7]=u1.w;
            } else {
#pragma unroll
                for (int jj = 0; jj < 8; ++jj) x[jj] = 0.f;
            }
#pragma unroll
            for (int jj = 0; jj < 8; ++jj) {
                short hi = f2bf_rne(x[jj]);
                bh[n][jj] = hi;
                bl[n][jj] = f2bf_rne(x[jj] - bf2f(hi));
            }
        }
#pragma unroll
        for (int m = 0; m < 4; ++m)
#pragma unroll
            for (int n = 0; n < 4; ++n) {
                acc[m][n] = __builtin_amdgcn_mfma_f32_16x16x32_bf16(ah[m], bh[n], acc[m][n], 0, 0, 0);
                acc[m][n] = __builtin_amdgcn_mfma_f32_16x16x32_bf16(al[m], bh[n], acc[m][n], 0, 0, 0);
                acc[m][n] = __builtin_amdgcn_mfma_f32_16x16x32_bf16(ah[m], bl[n], acc[m][n], 0, 0, 0);
            }
    }

#pragma unroll
    for (int m = 0; m < 4; ++m) {
#pragma unroll
        for (int n = 0; n < 4; ++n) {
            const int s = s0 + wn * 64 + n * 16 + fr;
            if (s >= NNP) continue;
#pragma unroll
            for (int jj = 0; jj < 4; ++jj) {
                const int h = wm * 64 + m * 16 + fc * 4 + jj;
                hpTb[h * NNP + s] = f2bf_rne(acc[m][n][jj]);
            }
        }
    }

    // fused e: per-thread dot over its 16 h, shfl over fc, LDS over wm
    __shared__ float esp[2][128], edp[2][128];
    float asv[4][4], adv[4][4];
#pragma unroll
    for (int m = 0; m < 4; ++m)
#pragma unroll
        for (int jj = 0; jj < 4; ++jj) {
            const int h = wm * 64 + m * 16 + fc * 4 + jj;
            asv[m][jj] = asrc[h];
            adv[m][jj] = adst[h];
        }
    float ps[4] = {0.f, 0.f, 0.f, 0.f}, pd[4] = {0.f, 0.f, 0.f, 0.f};
#pragma unroll
    for (int n = 0; n < 4; ++n)
#pragma unroll
        for (int m = 0; m < 4; ++m)
#pragma unroll
            for (int jj = 0; jj < 4; ++jj) {
                ps[n] += acc[m][n][jj] * asv[m][jj];
                pd[n] += acc[m][n][jj] * adv[m][jj];
            }
#pragma unroll
    for (int n = 0; n < 4; ++n) {
        ps[n] += __shfl_xor(ps[n], 16); ps[n] += __shfl_xor(ps[n], 32);
        pd[n] += __shfl_xor(pd[n], 16); pd[n] += __shfl_xor(pd[n], 32);
    }
    if (fc == 0) {
#pragma unroll
        for (int n = 0; n < 4; ++n) {
            esp[wm][wn * 64 + n * 16 + fr] = ps[n];
            edp[wm][wn * 64 + n * 16 + fr] = pd[n];
        }
    }
    __syncthreads();
    if (t < 128) {
        const int s = s0 + t;
        if (s < NNP) {
            const float es = esp[0][t] + esp[1][t];
            const float ed = edp[0][t] + edp[1][t];
            const long o = (long)b * NNP + s;
            esA[o] = es;                edA[o] = ed;
            e1sA[o] = __expf(es);       e2sA[o] = __expf(0.2f * es);
            e1dA[o] = __expf(ed);       e2dA[o] = __expf(0.2f * ed);
        }
    }
}

// ---------------- fragment-direct MFMA aggregation + optional fused LN/ReLU ----------------
template<int DO_LN>
__global__ __launch_bounds__(256) void k_aggr(const unsigned char* __restrict__ maskT,
                                              const short* __restrict__ hpT,
                                              const float* __restrict__ esA,
                                              const float* __restrict__ edA,
                                              const float* __restrict__ e1sA,
                                              const float* __restrict__ e2sA,
                                              const float* __restrict__ e1dA,
                                              const float* __restrict__ e2dA,
                                              const float* __restrict__ bias,
                                              const float* __restrict__ lng,
                                              const float* __restrict__ lnb,
                                              float* __restrict__ hout)
{
    const int b  = blockIdx.y;
    const int d0 = blockIdx.x * 128;
    const int t  = threadIdx.x;
    const int lane = t & 63, w = t >> 6;
    const int wm = w >> 1, wn = w & 1;
    const int fr = lane & 15, fc = lane >> 4;

    __shared__ float es_l[NNP], e1s_l[NNP], e2s_l[NNP];
    __shared__ float den_l[128];
    __shared__ float lngl[128], lnbl[128];

    for (int i = t; i < NNP; i += 256) {
        const long o = (long)b * NNP + i;
        es_l[i]  = esA[o];
        e1s_l[i] = e1sA[o];
        e2s_l[i] = e2sA[o];
    }
    if (DO_LN && t < 128) { lngl[t] = lng[t]; lnbl[t] = lnb[t]; }

    float edv[4], e1dv[4], e2dv[4];
#pragma unroll
    for (int m = 0; m < 4; ++m) {
        const int d = d0 + wm * 64 + m * 16 + fr;
        const bool v = d < NN;
        const long o = (long)b * NNP + d;
        edv[m]  = v ? edA[o]  : 0.f;
        e1dv[m] = v ? e1dA[o] : 0.f;
        e2dv[m] = v ? e2dA[o] : 0.f;
    }
    __syncthreads();

    f32x4 acc[4][4];
#pragma unroll
    for (int m = 0; m < 4; ++m)
#pragma unroll
        for (int n = 0; n < 4; ++n) acc[m][n] = (f32x4){0.f, 0.f, 0.f, 0.f};
    float den[4] = {0.f, 0.f, 0.f, 0.f};

    const unsigned char* mTb = maskT + (long)b * DP * NNP;
    const short* hTb = hpT + (long)b * NH * NNP;

    for (int kt = 0; kt < 13; ++kt) {
        const int sb = kt * 32 + fc * 8;
        short8v bf_[4];
#pragma unroll
        for (int n = 0; n < 4; ++n) {
            const int h = wn * 64 + n * 16 + fr;
            bf_[n] = *(const short8v*)&hTb[h * NNP + sb];
        }
        float es8[8], e18[8], e28[8];
#pragma unroll
        for (int jj = 0; jj < 8; ++jj) {
            es8[jj] = es_l[sb + jj];
            e18[jj] = e1s_l[sb + jj];
            e28[jj] = e2s_l[sb + jj];
        }
#pragma unroll
        for (int m = 0; m < 4; ++m) {
            const int d = d0 + wm * 64 + m * 16 + fr;
            const unsigned long long mk = *(const unsigned long long*)&mTb[(long)d * NNP + sb];
            short8v pv;
#pragma unroll
            for (int jj = 0; jj < 8; ++jj) {
                const float sc = es8[jj] + edv[m];
                float p = sc > 0.f ? e18[jj] * e1dv[m] : e28[jj] * e2dv[m];
                p = ((mk >> (8 * jj)) & 0xffULL) ? p : 0.f;
                den[m] += p;
                pv[jj] = f2bf_rne(p);
            }
#pragma unroll
            for (int n = 0; n < 4; ++n)
                acc[m][n] = __builtin_amdgcn_mfma_f32_16x16x32_bf16(pv, bf_[n], acc[m][n], 0, 0, 0);
        }
    }

#pragma unroll
    for (int m = 0; m < 4; ++m) {
        den[m] += __shfl_xor(den[m], 16);
        den[m] += __shfl_xor(den[m], 32);
    }
    if (wn == 0 && fc == 0) {
#pragma unroll
        for (int m = 0; m < 4; ++m) den_l[wm * 64 + m * 16 + fr] = den[m];
    }
    __syncthreads();

    float bvh[4];
#pragma unroll
    for (int n = 0; n < 4; ++n) bvh[n] = bias[wn * 64 + n * 16 + fr];

    float* hb = hout + (long)b * NN * NH;

    if (DO_LN) {
        __shared__ float Cm[32][132];
        for (int m = 0; m < 4; ++m) {
#pragma unroll
            for (int jj = 0; jj < 4; ++jj) {
                const int dl = wm * 64 + m * 16 + fc * 4 + jj;
                const float idn = 1.f / den_l[dl];
                const int r = wm * 16 + fc * 4 + jj;
#pragma unroll
                for (int n = 0; n < 4; ++n)
                    Cm[r][wn * 64 + n * 16 + fr] = acc[m][n][jj] * idn + bvh[n];
            }
            __syncthreads();
            {
                const int r = t >> 3, seg = t & 7;
                float s1 = 0.f, s2 = 0.f;
#pragma unroll
                for (int q = 0; q < 16; q += 4) {
                    float4 v = *(float4*)&Cm[r][seg * 16 + q];
                    s1 += v.x + v.y + v.z + v.w;
                    s2 += v.x * v.x + v.y * v.y + v.z * v.z + v.w * v.w;
                }
                s1 += __shfl_xor(s1, 1); s2 += __shfl_xor(s2, 1);
                s1 += __shfl_xor(s1, 2); s2 += __shfl_xor(s2, 2);
                s1 += __shfl_xor(s1, 4); s2 += __shfl_xor(s2, 4);
                const float mean = s1 * (1.f / 128.f);
                const float var  = s2 * (1.f / 128.f) - mean * mean;
                const float inv  = rsqrtf(fmaxf(var, 0.f) + LN_EPS);
                const int d = d0 + (r >> 4) * 64 + m * 16 + (r & 15);
                if (d < NN) {
                    float* po = hb + (long)d * NH;
#pragma unroll
                    for (int q = 0; q < 16; q += 4) {
                        const int cl = seg * 16 + q;
                        float4 v = *(float4*)&Cm[r][cl];
                        float4 o;
                        o.x = fmaxf((v.x - mean) * inv * lngl[cl]     + lnbl[cl],     0.f);
                        o.y = fmaxf((v.y - mean) * inv * lngl[cl + 1] + lnbl[cl + 1], 0.f);
                        o.z = fmaxf((v.z - mean) * inv * lngl[cl + 2] + lnbl[cl + 2], 0.f);
                        o.w = fmaxf((v.w - mean) * inv * lngl[cl + 3] + lnbl[cl + 3], 0.f);
                        *(float4*)&po[cl] = o;
                    }
                }
            }
            __syncthreads();
        }
    } else {
#pragma unroll
        for (int m = 0; m < 4; ++m) {
#pragma unroll
            for (int jj = 0; jj < 4; ++jj) {
                const int dl = wm * 64 + m * 16 + fc * 4 + jj;
                const int d = d0 + dl;
                if (d >= NN) continue;
                const float idn = 1.f / den_l[dl];
#pragma unroll
                for (int n = 0; n < 4; ++n) {
                    const int h = wn * 64 + n * 16 + fr;
                    hb[(long)d * NH + h] = acc[m][n][jj] * idn + bvh[n];
                }
            }
        }
    }
}

// ---------------- mean-pool over N + final linear ----------------
__global__ __launch_bounds__(128) void k_pool_lin(const float* __restrict__ h,
                                                  const float* __restrict__ Wl,
                                                  const float* __restrict__ bl,
                                                  float* __restrict__ out)
{
    const int b = blockIdx.x;
    const int t = threadIdx.x;
    const float* hb = h + (long)b * NN * NH;
    float s = 0.f;
    for (int n = 0; n < NN; ++n) s += hb[(long)n * NH + t];
    __shared__ float gl[128];
    gl[t] = s * (1.f / NN);
    __syncthreads();
    if (t < NCOUT) {
        float o = bl[t];
        for (int k = 0; k < NH; ++k) o += gl[k] * Wl[k * NCOUT + t];
        out[b * NCOUT + t] = o;
    }
}

extern "C" void kernel_launch(void* const* d_in, const int* in_sizes, int n_in,
                              void* d_out, int out_size, void* d_ws, size_t ws_size,
                              hipStream_t stream)
{
    const float* x    = (const float*)d_in[0];
    const float* adj  = (const float*)d_in[1];
    const float* Wadj = (const float*)d_in[4];
    const float* badj = (const float*)d_in[5];
    const float* W1   = (const float*)d_in[6];
    const float* as1  = (const float*)d_in[7];
    const float* ad1  = (const float*)d_in[8];
    const float* b1   = (const float*)d_in[9];
    const float* W2   = (const float*)d_in[10];
    const float* as2  = (const float*)d_in[11];
    const float* ad2  = (const float*)d_in[12];
    const float* b2   = (const float*)d_in[13];
    const float* lng  = (const float*)d_in[14];
    const float* lnb  = (const float*)d_in[15];
    const float* Wlin = (const float*)d_in[16];
    const float* blin = (const float*)d_in[17];
    float* out = (float*)d_out;

    char* ws = (char*)d_ws;
    unsigned char* maskT = (unsigned char*)ws;        // 256*512*416      = 54,525,952
    short* hpT  = (short*)(ws + 54525952);            // 256*128*416*2    = 27,262,976
    float* hbuf = (float*)(ws + 81788928);            // 256*400*128*4    = 52,428,800
    float* esA  = (float*)(ws + 134217728);           // 6 x 256*416*4
    float* edA  = (float*)(ws + 134643712);
    float* e1sA = (float*)(ws + 135069696);
    float* e2sA = (float*)(ws + 135495680);
    float* e1dA = (float*)(ws + 135921664);
    float* e2dA = (float*)(ws + 136347648);
    short* WtH  = (short*)(ws + 136773632);           // 425,984
    short* WtL  = (short*)(ws + 137199616);           // 425,984
    short* WT1H = (short*)(ws + 137625600);           // 32,768 each
    short* WT1L = (short*)(ws + 137658368);
    short* WT2H = (short*)(ws + 137691136);
    short* WT2L = (short*)(ws + 137723904);           // end 137,756,672

    k_wprep<<<dim3(13, 16), dim3(256), 0, stream>>>(Wadj, WtH, WtL);
    k_wprepW<<<dim3(64), dim3(256), 0, stream>>>(W1, WT1H, WT1L);
    k_wprepW<<<dim3(64), dim3(256), 0, stream>>>(W2, WT2H, WT2L);
    k_mask<<<dim3(4096), dim3(256), 0, stream>>>(adj, WtH, WtL, badj, maskT);

    // ---- GAT layer 1 ----
    k_hp<<<dim3(4, NB), dim3(256), 0, stream>>>(x, WT1H, WT1L, as1, ad1, hpT,
                                                esA, edA, e1sA, e2sA, e1dA, e2dA);
    k_aggr<1><<<dim3(4, NB), dim3(256), 0, stream>>>(maskT, hpT, esA, edA, e1sA, e2sA, e1dA, e2dA,
                                                     b1, lng, lnb, hbuf);

    // ---- GAT layer 2 ----
    k_hp<<<dim3(4, NB), dim3(256), 0, stream>>>(hbuf, WT2H, WT2L, as2, ad2, hpT,
                                                esA, edA, e1sA, e2sA, e1dA, e2dA);
    k_aggr<1><<<dim3(4, NB), dim3(256), 0, stream>>>(maskT, hpT, esA, edA, e1sA, e2sA, e1dA, e2dA,
                                                     b2, lng, lnb, hbuf);

    // ---- GAT layer 3 (W2 again, no LN/ReLU) ----
    k_hp<<<dim3(4, NB), dim3(256), 0, stream>>>(hbuf, WT2H, WT2L, as2, ad2, hpT,
                                                esA, edA, e1sA, e2sA, e1dA, e2dA);
    k_aggr<0><<<dim3(4, NB), dim3(256), 0, stream>>>(maskT, hpT, esA, edA, e1sA, e2sA, e1dA, e2dA,
                                                     b2, lng, lnb, hbuf);

    k_pool_lin<<<dim3(NB), dim3(128), 0, stream>>>(hbuf, Wlin, blin, out);
}

// Round 11
// 523.835 us; speedup vs baseline: 1.5732x; 1.0624x over previous
//
#include <hip/hip_runtime.h>
#include <hip/hip_bf16.h>
#include <math.h>

#define NB 256
#define NN 400
#define NH 128
#define NCOUT 16
#define NNP 416   // padded N (13*32 = 52*8)
#define DP  512   // padded dst rows for maskT
#define KP  416   // padded K for W_adj prep

static constexpr float LOGIT_THRESH = 0.40546510810816444f; // ln(1.5)
static constexpr float LN_EPS = 1e-5f;

typedef __attribute__((ext_vector_type(8))) short short8v;
typedef __attribute__((ext_vector_type(4))) float f32x4;

static __device__ __forceinline__ short f2bf_rne(float f) {
    unsigned u = __float_as_uint(f);
    unsigned r = (u + 0x7fff + ((u >> 16) & 1)) >> 16;
    return (short)r;
}
static __device__ __forceinline__ float bf2f(short s) {
    return __uint_as_float(((unsigned)(unsigned short)s) << 16);
}

// packed f32 pair -> 2x bf16 (RNE) in one v_cvt_pk_bf16_f32
static __device__ __forceinline__ unsigned pk_bf16(float a, float b) {
    __hip_bfloat162 h = __float22bfloat162_rn(make_float2(a, b));
    unsigned r;
    __builtin_memcpy(&r, &h, 4);
    return r;
}
// RNE hi/lo split of a pair: hw = packed hi bf16s, lw = packed lo bf16s
static __device__ __forceinline__ void split_pair(float a, float b, unsigned& hw, unsigned& lw) {
    hw = pk_bf16(a, b);
    float ha = __uint_as_float(hw << 16);
    float hb = __uint_as_float(hw & 0xffff0000u);
    lw = pk_bf16(a - ha, b - hb);
}
static __device__ __forceinline__ void split8v(const float x[8], short8v& hv, short8v& lv) {
    unsigned* hp = (unsigned*)&hv;
    unsigned* lp = (unsigned*)&lv;
#pragma unroll
    for (int q = 0; q < 4; ++q) split_pair(x[2 * q], x[2 * q + 1], hp[q], lp[q]);
}

// async global->LDS DMA, 16B per lane; lptr is wave-uniform base, HW adds lane*16
static __device__ __forceinline__ void gload16(const void* g, void* l) {
    __builtin_amdgcn_global_load_lds((const __attribute__((address_space(1))) void*)g,
                                     (__attribute__((address_space(3))) void*)l, 16, 0, 0);
}

// ---------------- W_adj -> bf16 hi/lo, transposed + padded ----------------
__global__ __launch_bounds__(256) void k_wprep(const float* __restrict__ W,
                                               short* __restrict__ WtH,
                                               short* __restrict__ WtL)
{
    const int k0 = blockIdx.x * 32, d0 = blockIdx.y * 32;
    __shared__ float tile[32][33];
    const int t = threadIdx.x, cc = t & 31, rr = t >> 5;
#pragma unroll
    for (int i = 0; i < 4; ++i) {
        int k = k0 + rr + i * 8, d = d0 + cc;
        tile[rr + i * 8][cc] = (k < NN && d < NN) ? W[k * NN + d] : 0.f;
    }
    __syncthreads();
#pragma unroll
    for (int i = 0; i < 4; ++i) {
        int dr = rr + i * 8;
        int d = d0 + dr, k = k0 + cc;
        float v = tile[cc][dr];
        short h = f2bf_rne(v);
        WtH[d * KP + k] = h;
        WtL[d * KP + k] = f2bf_rne(v - bf2f(h));
    }
}

// ---------------- W (128x128) -> bf16 hi/lo transposed: WT[h][k] ----------------
__global__ __launch_bounds__(256) void k_wprepW(const float* __restrict__ W,
                                                short* __restrict__ WTH,
                                                short* __restrict__ WTL)
{
    const int t = blockIdx.x * 256 + threadIdx.x;   // 16384
    const int h = t >> 7, k = t & 127;
    float v = W[k * NH + h];
    short hi = f2bf_rne(v);
    WTH[h * NH + k] = hi;
    WTL[h * NH + k] = f2bf_rne(v - bf2f(hi));
}

// ---------------- mask GEMM -> tiled maskT[b][dg][sc][16][8] ----------------
// dbuf + counted-vmcnt pipeline (r9 structure), packed-RNE A split.
__global__ __launch_bounds__(256) void k_mask(const float* __restrict__ adj,
                                              const short* __restrict__ WtH,
                                              const short* __restrict__ WtL,
                                              const float* __restrict__ badj,
                                              unsigned char* __restrict__ maskT)
{
    // 1-D grid 4096; group the 4 d0-members of each (b,s0) A-panel on one XCD.
    const int j   = blockIdx.x;
    const int xcd = j & 7;
    const int li  = j >> 3;
    const int panel  = xcd * 128 + (li >> 2);
    const int member = li & 3;
    const int b  = panel >> 2;
    const int s0 = (panel & 3) * 128;
    const int d0 = member * 128;

    const int t = threadIdx.x;
    const int lane = t & 63, w = t >> 6;
    const int wm = w >> 1, wn = w & 1;
    const int fr = lane & 15, fc = lane >> 4;

    __shared__ float As[2][128 * 32];
    __shared__ short Bhs[2][128 * 32];
    __shared__ short Bls[2][128 * 32];

    const float* adjb = adj + (long)b * NN * NN;

    long aG[4];
    int  aRow[4];
#pragma unroll
    for (int i = 0; i < 4; ++i) {
        int rloc = w * 32 + i * 8 + (lane >> 3);
        aRow[i] = rloc;
        int srow = s0 + rloc; srow = srow < NN ? srow : NN - 1;
        int c = (lane & 7) ^ (rloc & 7);
        aG[i] = (long)srow * NN + c * 4;
    }
    long bG[2];
#pragma unroll
    for (int i = 0; i < 2; ++i) {
        int rloc = w * 32 + i * 16 + (lane >> 2);
        int drow = d0 + rloc;
        int c = (lane & 3) ^ ((rloc >> 1) & 3);
        bG[i] = (long)drow * KP + c * 8;
    }

    f32x4 acc[4][4];
#pragma unroll
    for (int mi = 0; mi < 4; ++mi)
#pragma unroll
        for (int ni = 0; ni < 4; ++ni) acc[mi][ni] = (f32x4){0.f, 0.f, 0.f, 0.f};

    const int ca0 = (2 * fc) ^ (fr & 7);
    const int ca1 = (2 * fc + 1) ^ (fr & 7);
    const int cb  = fc ^ ((fr >> 1) & 3);

    #define STAGE(KT, BUF)                                                            \
    do {                                                                              \
        const int k0_ = (KT) * 32;                                                    \
        _Pragma("unroll")                                                             \
        for (int i = 0; i < 4; ++i) {                                                 \
            long gi = aG[i] + k0_;                                                    \
            if ((KT) == 12) {                                                         \
                int c = (lane & 7) ^ (aRow[i] & 7);                                   \
                if (c >= 4) gi = aG[i] - (long)c * 4;                                 \
            }                                                                         \
            gload16(adjb + gi, (char*)&As[BUF][0] + (w * 32 + i * 8) * 128);          \
        }                                                                             \
        _Pragma("unroll")                                                             \
        for (int i = 0; i < 2; ++i) {                                                 \
            gload16(WtH + bG[i] + k0_, (char*)&Bhs[BUF][0] + (w * 32 + i * 16) * 64); \
            gload16(WtL + bG[i] + k0_, (char*)&Bls[BUF][0] + (w * 32 + i * 16) * 64); \
        }                                                                             \
    } while (0)

    STAGE(0, 0);
    asm volatile("s_waitcnt vmcnt(0)" ::: "memory");
    __builtin_amdgcn_s_barrier();

    int cur = 0;
    for (int kt = 0; kt < 13; ++kt) {
        __builtin_amdgcn_s_barrier();
        if (kt < 12) STAGE(kt + 1, cur ^ 1);
        if (kt < 12) asm volatile("s_waitcnt vmcnt(8)" ::: "memory");
        else         asm volatile("s_waitcnt vmcnt(0)" ::: "memory");
        __builtin_amdgcn_s_barrier();
        __builtin_amdgcn_sched_barrier(0);

        short8v ah[4], al[4], bh[4], bl[4];
#pragma unroll
        for (int m = 0; m < 4; ++m) {
            const int row = wm * 64 + m * 16 + fr;
            float4 u0 = *(const float4*)((const char*)&As[cur][0] + row * 128 + ca0 * 16);
            float4 u1 = *(const float4*)((const char*)&As[cur][0] + row * 128 + ca1 * 16);
            float x[8] = {u0.x, u0.y, u0.z, u0.w, u1.x, u1.y, u1.z, u1.w};
            split8v(x, ah[m], al[m]);
        }
#pragma unroll
        for (int n = 0; n < 4; ++n) {
            const int row = wn * 64 + n * 16 + fr;
            bh[n] = *(const short8v*)((const char*)&Bhs[cur][0] + row * 64 + cb * 16);
            bl[n] = *(const short8v*)((const char*)&Bls[cur][0] + row * 64 + cb * 16);
        }
#pragma unroll
        for (int mi = 0; mi < 4; ++mi)
#pragma unroll
            for (int ni = 0; ni < 4; ++ni) {
                acc[mi][ni] = __builtin_amdgcn_mfma_f32_16x16x32_bf16(ah[mi], bh[ni], acc[mi][ni], 0, 0, 0);
                acc[mi][ni] = __builtin_amdgcn_mfma_f32_16x16x32_bf16(al[mi], bh[ni], acc[mi][ni], 0, 0, 0);
                acc[mi][ni] = __builtin_amdgcn_mfma_f32_16x16x32_bf16(ah[mi], bl[ni], acc[mi][ni], 0, 0, 0);
            }
        cur ^= 1;
    }
    #undef STAGE

    // epilogue -> tiled maskT[b][dg][sc][16][8]
    unsigned char* mTb = maskT + (long)b * 32 * 52 * 128;
    const int dgbase = (d0 >> 4) + wn * 4;                  // + ni
    const int scbase = ((s0 + wm * 64) >> 3) + (fc >> 1);   // + mi*2
    const int off8   = (fc & 1) * 4;
#pragma unroll
    for (int ni = 0; ni < 4; ++ni) {
        const int d = d0 + wn * 64 + ni * 16 + fr;
        if (d >= NN) continue;
        const float bv = badj[d];
#pragma unroll
        for (int mi = 0; mi < 4; ++mi) {
            const int s_cb = s0 + wm * 64 + mi * 16 + fc * 4;   // this thread's 4-byte base
            if (s_cb >= NNP) continue;
            uchar4 pk;
#pragma unroll
            for (int jj = 0; jj < 4; ++jj) {
                const int s = s_cb + jj;
                bool v = (s < NN) && ((acc[mi][ni][jj] + bv) > LOGIT_THRESH || s == d);
                ((unsigned char*)&pk)[jj] = v ? 1 : 0;
            }
            *(uchar4*)&mTb[((long)(dgbase + ni) * 52 + (scbase + mi * 2)) * 128 + fr * 8 + off8] = pk;
        }
    }
}

// ---------------- hpT = (hin @ W)^T as bf16 + FUSED exp tables ----------------
__global__ __launch_bounds__(256) void k_hp(const float* __restrict__ hin,
                                            const short* __restrict__ WTH,
                                            const short* __restrict__ WTL,
                                            const float* __restrict__ asrc,
                                            const float* __restrict__ adst,
                                            short* __restrict__ hpT,
                                            float* __restrict__ e1sA, float* __restrict__ e2sA,
                                            float* __restrict__ e1dA, float* __restrict__ e2dA)
{
    const int b  = blockIdx.y;
    const int s0 = blockIdx.x * 128;
    const int t  = threadIdx.x;
    const int lane = t & 63, w = t >> 6;
    const int wm = w >> 1, wn = w & 1;   // wm: h-half, wn: s-half
    const int fr = lane & 15, fc = lane >> 4;

    const float* hb = hin + (long)b * NN * NH;
    short* hpTb = hpT + (long)b * NH * NNP;

    f32x4 acc[4][4];
#pragma unroll
    for (int m = 0; m < 4; ++m)
#pragma unroll
        for (int n = 0; n < 4; ++n) acc[m][n] = (f32x4){0.f, 0.f, 0.f, 0.f};

    for (int kt = 0; kt < 4; ++kt) {
        const int k0 = kt * 32;
        short8v ah[4], al[4], bh[4], bl[4];
#pragma unroll
        for (int m = 0; m < 4; ++m) {
            const int h = wm * 64 + m * 16 + fr;
            ah[m] = *(const short8v*)&WTH[h * NH + k0 + fc * 8];
            al[m] = *(const short8v*)&WTL[h * NH + k0 + fc * 8];
        }
#pragma unroll
        for (int n = 0; n < 4; ++n) {
            const int s = s0 + wn * 64 + n * 16 + fr;
            float x[8];
            if (s < NN) {
                float4 u0 = *(const float4*)&hb[(long)s * NH + k0 + fc * 8];
                float4 u1 = *(const float4*)&hb[(long)s * NH + k0 + fc * 8 + 4];
                x[0]=u0.x; x[1]=u0.y; x[2]=u0.z; x[3]=u0.w;
                x[4]=u1.x; x[5]=u1.y; x[6]=u1.z; x[7]=u1.w;
            } else {
#pragma unroll
                for (int jj = 0; jj < 8; ++jj) x[jj] = 0.f;
            }
            split8v(x, bh[n], bl[n]);
        }
#pragma unroll
        for (int m = 0; m < 4; ++m)
#pragma unroll
            for (int n = 0; n < 4; ++n) {
                acc[m][n] = __builtin_amdgcn_mfma_f32_16x16x32_bf16(ah[m], bh[n], acc[m][n], 0, 0, 0);
                acc[m][n] = __builtin_amdgcn_mfma_f32_16x16x32_bf16(al[m], bh[n], acc[m][n], 0, 0, 0);
                acc[m][n] = __builtin_amdgcn_mfma_f32_16x16x32_bf16(ah[m], bl[n], acc[m][n], 0, 0, 0);
            }
    }

#pragma unroll
    for (int m = 0; m < 4; ++m) {
#pragma unroll
        for (int n = 0; n < 4; ++n) {
            const int s = s0 + wn * 64 + n * 16 + fr;
            if (s >= NNP) continue;
#pragma unroll
            for (int jj = 0; jj < 4; ++jj) {
                const int h = wm * 64 + m * 16 + fc * 4 + jj;
                hpTb[h * NNP + s] = f2bf_rne(acc[m][n][jj]);
            }
        }
    }

    // fused e: per-thread dot over its 16 h, shfl over fc, LDS over wm
    __shared__ float esp[2][128], edp[2][128];
    float asv[4][4], adv[4][4];
#pragma unroll
    for (int m = 0; m < 4; ++m)
#pragma unroll
        for (int jj = 0; jj < 4; ++jj) {
            const int h = wm * 64 + m * 16 + fc * 4 + jj;
            asv[m][jj] = asrc[h];
            adv[m][jj] = adst[h];
        }
    float ps[4] = {0.f, 0.f, 0.f, 0.f}, pd[4] = {0.f, 0.f, 0.f, 0.f};
#pragma unroll
    for (int n = 0; n < 4; ++n)
#pragma unroll
        for (int m = 0; m < 4; ++m)
#pragma unroll
            for (int jj = 0; jj < 4; ++jj) {
                ps[n] += acc[m][n][jj] * asv[m][jj];
                pd[n] += acc[m][n][jj] * adv[m][jj];
            }
#pragma unroll
    for (int n = 0; n < 4; ++n) {
        ps[n] += __shfl_xor(ps[n], 16); ps[n] += __shfl_xor(ps[n], 32);
        pd[n] += __shfl_xor(pd[n], 16); pd[n] += __shfl_xor(pd[n], 32);
    }
    if (fc == 0) {
#pragma unroll
        for (int n = 0; n < 4; ++n) {
            esp[wm][wn * 64 + n * 16 + fr] = ps[n];
            edp[wm][wn * 64 + n * 16 + fr] = pd[n];
        }
    }
    __syncthreads();
    if (t < 128) {
        const int s = s0 + t;
        if (s < NNP) {
            const float es = esp[0][t] + esp[1][t];
            const float ed = edp[0][t] + edp[1][t];
            const long o = (long)b * NNP + s;
            e1sA[o] = __expf(es);       e2sA[o] = __expf(0.2f * es);
            e1dA[o] = __expf(ed);       e2dA[o] = __expf(0.2f * ed);
        }
    }
}

// ---------------- MFMA aggregation: max-form P, coalesced tiled-mask reads, fused LN ----------------
template<int DO_LN>
__global__ __launch_bounds__(256) void k_aggr(const unsigned char* __restrict__ maskT,
                                              const short* __restrict__ hpT,
                                              const float* __restrict__ e1sA,
                                              const float* __restrict__ e2sA,
                                              const float* __restrict__ e1dA,
                                              const float* __restrict__ e2dA,
                                              const float* __restrict__ bias,
                                              const float* __restrict__ lng,
                                              const float* __restrict__ lnb,
                                              float* __restrict__ hout)
{
    const int b  = blockIdx.y;
    const int d0 = blockIdx.x * 128;
    const int t  = threadIdx.x;
    const int lane = t & 63, w = t >> 6;
    const int wm = w >> 1, wn = w & 1;
    const int fr = lane & 15, fc = lane >> 4;

    __shared__ float e1s_l[NNP], e2s_l[NNP];
    __shared__ float den_l[128];
    __shared__ float lngl[128], lnbl[128];

    for (int i = t; i < NNP; i += 256) {
        const long o = (long)b * NNP + i;
        e1s_l[i] = e1sA[o];
        e2s_l[i] = e2sA[o];
    }
    if (DO_LN && t < 128) { lngl[t] = lng[t]; lnbl[t] = lnb[t]; }

    float e1dv[4], e2dv[4];
#pragma unroll
    for (int m = 0; m < 4; ++m) {
        const int d = d0 + wm * 64 + m * 16 + fr;
        const bool v = d < NN;
        const long o = (long)b * NNP + (v ? d : 0);
        e1dv[m] = v ? e1dA[o] : 0.f;
        e2dv[m] = v ? e2dA[o] : 0.f;
    }
    __syncthreads();

    f32x4 acc[4][4];
#pragma unroll
    for (int m = 0; m < 4; ++m)
#pragma unroll
        for (int n = 0; n < 4; ++n) acc[m][n] = (f32x4){0.f, 0.f, 0.f, 0.f};
    float den[4] = {0.f, 0.f, 0.f, 0.f};

    // tiled mask base: dg = d0/16 + wm*4 + m, sc = kt*4 + fc, lane row = fr
    const unsigned char* mbase = maskT + (((long)b * 32 + (d0 >> 4) + wm * 4) * 52) * 128 + fr * 8;
    const short* hTb = hpT + (long)b * NH * NNP;

    for (int kt = 0; kt < 13; ++kt) {
        const int sb = kt * 32 + fc * 8;
        short8v bf_[4];
#pragma unroll
        for (int n = 0; n < 4; ++n) {
            const int h = wn * 64 + n * 16 + fr;
            bf_[n] = *(const short8v*)&hTb[h * NNP + sb];
        }
        float4 e1a = *(const float4*)&e1s_l[sb];
        float4 e1b = *(const float4*)&e1s_l[sb + 4];
        float4 e2a = *(const float4*)&e2s_l[sb];
        float4 e2b = *(const float4*)&e2s_l[sb + 4];
        float e18[8] = {e1a.x, e1a.y, e1a.z, e1a.w, e1b.x, e1b.y, e1b.z, e1b.w};
        float e28[8] = {e2a.x, e2a.y, e2a.z, e2a.w, e2b.x, e2b.y, e2b.z, e2b.w};
        const long scoff = (long)(kt * 4 + fc) * 128;
#pragma unroll
        for (int m = 0; m < 4; ++m) {
            const unsigned long long mk = *(const unsigned long long*)(mbase + (long)m * 52 * 128 + scoff);
            short8v pv;
            unsigned* pw = (unsigned*)&pv;
#pragma unroll
            for (int q = 0; q < 4; ++q) {
                // p = exp(leaky(es+ed)) = max(e1s*e1d, e2s*e2d)  [exp monotone]
                float p0 = fmaxf(e18[2 * q] * e1dv[m],     e28[2 * q] * e2dv[m]);
                float p1 = fmaxf(e18[2 * q + 1] * e1dv[m], e28[2 * q + 1] * e2dv[m]);
                p0 = ((mk >> (16 * q)) & 0xffULL)     ? p0 : 0.f;
                p1 = ((mk >> (16 * q + 8)) & 0xffULL) ? p1 : 0.f;
                den[m] += p0 + p1;
                pw[q] = pk_bf16(p0, p1);
            }
#pragma unroll
            for (int n = 0; n < 4; ++n)
                acc[m][n] = __builtin_amdgcn_mfma_f32_16x16x32_bf16(pv, bf_[n], acc[m][n], 0, 0, 0);
        }
    }

#pragma unroll
    for (int m = 0; m < 4; ++m) {
        den[m] += __shfl_xor(den[m], 16);
        den[m] += __shfl_xor(den[m], 32);
    }
    if (wn == 0 && fc == 0) {
#pragma unroll
        for (int m = 0; m < 4; ++m) den_l[wm * 64 + m * 16 + fr] = den[m];
    }
    __syncthreads();

    float bvh[4];
#pragma unroll
    for (int n = 0; n < 4; ++n) bvh[n] = bias[wn * 64 + n * 16 + fr];

    float* hb = hout + (long)b * NN * NH;

    if (DO_LN) {
        __shared__ float Cm[32][132];
        for (int m = 0; m < 4; ++m) {
#pragma unroll
            for (int jj = 0; jj < 4; ++jj) {
                const int dl = wm * 64 + m * 16 + fc * 4 + jj;
                const float idn = 1.f / den_l[dl];
                const int r = wm * 16 + fc * 4 + jj;
#pragma unroll
                for (int n = 0; n < 4; ++n)
                    Cm[r][wn * 64 + n * 16 + fr] = acc[m][n][jj] * idn + bvh[n];
            }
            __syncthreads();
            {
                const int r = t >> 3, seg = t & 7;
                float s1 = 0.f, s2 = 0.f;
#pragma unroll
                for (int q = 0; q < 16; q += 4) {
                    float4 v = *(float4*)&Cm[r][seg * 16 + q];
                    s1 += v.x + v.y + v.z + v.w;
                    s2 += v.x * v.x + v.y * v.y + v.z * v.z + v.w * v.w;
                }
                s1 += __shfl_xor(s1, 1); s2 += __shfl_xor(s2, 1);
                s1 += __shfl_xor(s1, 2); s2 += __shfl_xor(s2, 2);
                s1 += __shfl_xor(s1, 4); s2 += __shfl_xor(s2, 4);
                const float mean = s1 * (1.f / 128.f);
                const float var  = s2 * (1.f / 128.f) - mean * mean;
                const float inv  = rsqrtf(fmaxf(var, 0.f) + LN_EPS);
                const int d = d0 + (r >> 4) * 64 + m * 16 + (r & 15);
                if (d < NN) {
                    float* po = hb + (long)d * NH;
#pragma unroll
                    for (int q = 0; q < 16; q += 4) {
                        const int cl = seg * 16 + q;
                        float4 v = *(float4*)&Cm[r][cl];
                        float4 o;
                        o.x = fmaxf((v.x - mean) * inv * lngl[cl]     + lnbl[cl],     0.f);
                        o.y = fmaxf((v.y - mean) * inv * lngl[cl + 1] + lnbl[cl + 1], 0.f);
                        o.z = fmaxf((v.z - mean) * inv * lngl[cl + 2] + lnbl[cl + 2], 0.f);
                        o.w = fmaxf((v.w - mean) * inv * lngl[cl + 3] + lnbl[cl + 3], 0.f);
                        *(float4*)&po[cl] = o;
                    }
                }
            }
            __syncthreads();
        }
    } else {
#pragma unroll
        for (int m = 0; m < 4; ++m) {
#pragma unroll
            for (int jj = 0; jj < 4; ++jj) {
                const int dl = wm * 64 + m * 16 + fc * 4 + jj;
                const int d = d0 + dl;
                if (d >= NN) continue;
                const float idn = 1.f / den_l[dl];
#pragma unroll
                for (int n = 0; n < 4; ++n) {
                    const int h = wn * 64 + n * 16 + fr;
                    hb[(long)d * NH + h] = acc[m][n][jj] * idn + bvh[n];
                }
            }
        }
    }
}

// ---------------- mean-pool over N + final linear ----------------
__global__ __launch_bounds__(128) void k_pool_lin(const float* __restrict__ h,
                                                  const float* __restrict__ Wl,
                                                  const float* __restrict__ bl,
                                                  float* __restrict__ out)
{
    const int b = blockIdx.x;
    const int t = threadIdx.x;
    const float* hb = h + (long)b * NN * NH;
    float s = 0.f;
    for (int n = 0; n < NN; ++n) s += hb[(long)n * NH + t];
    __shared__ float gl[128];
    gl[t] = s * (1.f / NN);
    __syncthreads();
    if (t < NCOUT) {
        float o = bl[t];
        for (int k = 0; k < NH; ++k) o += gl[k] * Wl[k * NCOUT + t];
        out[b * NCOUT + t] = o;
    }
}

extern "C" void kernel_launch(void* const* d_in, const int* in_sizes, int n_in,
                              void* d_out, int out_size, void* d_ws, size_t ws_size,
                              hipStream_t stream)
{
    const float* x    = (const float*)d_in[0];
    const float* adj  = (const float*)d_in[1];
    const float* Wadj = (const float*)d_in[4];
    const float* badj = (const float*)d_in[5];
    const float* W1   = (const float*)d_in[6];
    const float* as1  = (const float*)d_in[7];
    const float* ad1  = (const float*)d_in[8];
    const float* b1   = (const float*)d_in[9];
    const float* W2   = (const float*)d_in[10];
    const float* as2  = (const float*)d_in[11];
    const float* ad2  = (const float*)d_in[12];
    const float* b2   = (const float*)d_in[13];
    const float* lng  = (const float*)d_in[14];
    const float* lnb  = (const float*)d_in[15];
    const float* Wlin = (const float*)d_in[16];
    const float* blin = (const float*)d_in[17];
    float* out = (float*)d_out;

    char* ws = (char*)d_ws;
    unsigned char* maskT = (unsigned char*)ws;        // 256*32*52*128    = 54,525,952
    short* hpT  = (short*)(ws + 54525952);            // 256*128*416*2    = 27,262,976
    float* hbuf = (float*)(ws + 81788928);            // 256*400*128*4    = 52,428,800
    float* e1sA = (float*)(ws + 135069696);           // 4 x 256*416*4
    float* e2sA = (float*)(ws + 135495680);
    float* e1dA = (float*)(ws + 135921664);
    float* e2dA = (float*)(ws + 136347648);
    short* WtH  = (short*)(ws + 136773632);           // 425,984
    short* WtL  = (short*)(ws + 137199616);           // 425,984
    short* WT1H = (short*)(ws + 137625600);           // 32,768 each
    short* WT1L = (short*)(ws + 137658368);
    short* WT2H = (short*)(ws + 137691136);
    short* WT2L = (short*)(ws + 137723904);           // end 137,756,672

    k_wprep<<<dim3(13, 16), dim3(256), 0, stream>>>(Wadj, WtH, WtL);
    k_wprepW<<<dim3(64), dim3(256), 0, stream>>>(W1, WT1H, WT1L);
    k_wprepW<<<dim3(64), dim3(256), 0, stream>>>(W2, WT2H, WT2L);
    k_mask<<<dim3(4096), dim3(256), 0, stream>>>(adj, WtH, WtL, badj, maskT);

    // ---- GAT layer 1 ----
    k_hp<<<dim3(4, NB), dim3(256), 0, stream>>>(x, WT1H, WT1L, as1, ad1, hpT,
                                                e1sA, e2sA, e1dA, e2dA);
    k_aggr<1><<<dim3(4, NB), dim3(256), 0, stream>>>(maskT, hpT, e1sA, e2sA, e1dA, e2dA,
                                                     b1, lng, lnb, hbuf);

    // ---- GAT layer 2 ----
    k_hp<<<dim3(4, NB), dim3(256), 0, stream>>>(hbuf, WT2H, WT2L, as2, ad2, hpT,
                                                e1sA, e2sA, e1dA, e2dA);
    k_aggr<1><<<dim3(4, NB), dim3(256), 0, stream>>>(maskT, hpT, e1sA, e2sA, e1dA, e2dA,
                                                     b2, lng, lnb, hbuf);

    // ---- GAT layer 3 (W2 again, no LN/ReLU) ----
    k_hp<<<dim3(4, NB), dim3(256), 0, stream>>>(hbuf, WT2H, WT2L, as2, ad2, hpT,
                                                e1sA, e2sA, e1dA, e2dA);
    k_aggr<0><<<dim3(4, NB), dim3(256), 0, stream>>>(maskT, hpT, e1sA, e2sA, e1dA, e2dA,
                                                     b2, lng, lnb, hbuf);

    k_pool_lin<<<dim3(NB), dim3(128), 0, stream>>>(hbuf, Wlin, blin, out);
}